// Round 6
// baseline (363.680 us; speedup 1.0000x reference)
//
#include <hip/hip_runtime.h>
#include <hip/hip_bf16.h>
#include <cstdint>
#include <cstddef>

#define NBLK 512          // binning blocks
#define BSH 8             // bucket shift: 256 nodes per bucket

typedef short bf16x8 __attribute__((ext_vector_type(8)));
typedef float f32x4 __attribute__((ext_vector_type(4)));

__device__ __forceinline__ float leaky02(float x) { return x > 0.f ? x : 0.2f * x; }
__device__ __forceinline__ float bflo(unsigned u) { return __uint_as_float(u << 16); }
__device__ __forceinline__ float bfhi(unsigned u) { return __uint_as_float(u & 0xFFFF0000u); }
__device__ __forceinline__ unsigned short f2bf(float f) {
  __hip_bfloat16 h = __float2bfloat16(f);
  return *(unsigned short*)&h;
}
__device__ __forceinline__ unsigned pack2bf(float a, float b) {
  return (unsigned)f2bf(a) | ((unsigned)f2bf(b) << 16);
}

// ---------------- CSR build: hist (+ fused weight transpose) ----------------
__global__ void bucket_hist(const int* __restrict__ dst, int* __restrict__ T,
                            int E, int N, int NB, int echunk, int nchunk,
                            const float* __restrict__ w1, const float* __restrict__ w2,
                            const float* __restrict__ w3,
                            unsigned short* __restrict__ t1, unsigned short* __restrict__ t2,
                            unsigned short* __restrict__ t3) {
  int b = blockIdx.x, t = threadIdx.x;
  if (b >= NBLK) {          // prep_w part: W[128][NO] fp32 -> Wt[NO][128] bf16
    int bb = b - NBLK;
    const float* W; unsigned short* Tw; int NO; int e;
    if (bb < 64)      { W = w1; Tw = t1; NO = 128; e = bb * 256 + t; }
    else if (bb < 128){ W = w2; Tw = t2; NO = 128; e = (bb - 64) * 256 + t; }
    else              { W = w3; Tw = t3; NO = 64;  e = (bb - 128) * 256 + t; }
    int c = e >> 7, k = e & 127;
    Tw[c * 128 + k] = f2bf(W[k * NO + c]);
    return;
  }
  __shared__ int hist[512];
  hist[t] = 0; hist[t + 256] = 0;
  __syncthreads();
  int e0 = b * echunk, e1 = min(E, e0 + echunk);
  for (int e = e0 + t; e < e1; e += 256) atomicAdd(&hist[dst[e] >> BSH], 1);
  int n0 = b * nchunk, n1 = min(N, n0 + nchunk);
  for (int nn = n0 + t; nn < n1; nn += 256) atomicAdd(&hist[nn >> BSH], 1);
  __syncthreads();
  for (int k = t; k < NB; k += 256) if (hist[k]) atomicAdd(&T[k], hist[k]);
}

// 1-block scan of bucket totals -> bases B[0..NB] + cursors C[0..NB)
__global__ void scan_small(const int* __restrict__ T, int* __restrict__ B,
                           int* __restrict__ C, int NB) {
  __shared__ int wsum[8];
  int t = threadIdx.x;
  int val = (t < NB) ? T[t] : 0;
  int lane = t & 63, wid = t >> 6;
  int incl = val;
  for (int off = 1; off < 64; off <<= 1) {
    int o = __shfl_up(incl, off);
    if (lane >= off) incl += o;
  }
  if (lane == 63) wsum[wid] = incl;
  __syncthreads();
  if (t == 0) { int r = 0; for (int i = 0; i < 8; ++i) { int x = wsum[i]; wsum[i] = r; r += x; } }
  __syncthreads();
  int excl = incl - val + wsum[wid];
  if (t <= NB) B[t] = excl;
  if (t < NB) C[t] = excl;
}

// count chunk -> claim ranges -> scatter payloads (src | localdst<<24)
__global__ void bucketB2(const int* __restrict__ src, const int* __restrict__ dst,
                         int* __restrict__ C, unsigned* __restrict__ binned,
                         int E, int N, int NB, int echunk, int nchunk) {
  __shared__ int hist[512];
  __shared__ int cur[512];
  int b = blockIdx.x, t = threadIdx.x;
  hist[t] = 0; hist[t + 256] = 0;
  __syncthreads();
  int e0 = b * echunk, e1 = min(E, e0 + echunk);
  for (int e = e0 + t; e < e1; e += 256) atomicAdd(&hist[dst[e] >> BSH], 1);
  int n0 = b * nchunk, n1 = min(N, n0 + nchunk);
  for (int nn = n0 + t; nn < n1; nn += 256) atomicAdd(&hist[nn >> BSH], 1);
  __syncthreads();
  for (int k = t; k < 512; k += 256) {
    int c = hist[k];
    cur[k] = c ? atomicAdd(&C[k], c) : 0;
  }
  __syncthreads();
  for (int e = e0 + t; e < e1; e += 256) {
    int d = dst[e];
    int k = d >> BSH;
    int pos = atomicAdd(&cur[k], 1);
    binned[pos] = (unsigned)src[e] | ((unsigned)(d & 255) << 24);
  }
  for (int nn = n0 + t; nn < n1; nn += 256) {
    int k = nn >> BSH;
    int pos = atomicAdd(&cur[k], 1);
    binned[pos] = (unsigned)nn | ((unsigned)(nn & 255) << 24);
  }
}

// per-bucket counting sort -> rowp + col
__global__ void bucketC2(const unsigned* __restrict__ binned, const int* __restrict__ B,
                         int* __restrict__ rowp, int* __restrict__ col, int N) {
  __shared__ int cnt2[256];
  __shared__ int cur2[256];
  __shared__ int wsum[4];
  int k = blockIdx.x, t = threadIdx.x;
  int base = B[k];
  int end  = B[k + 1];
  cnt2[t] = 0;
  __syncthreads();
  for (int e = base + t; e < end; e += 256) atomicAdd(&cnt2[binned[e] >> 24], 1);
  __syncthreads();
  int v = cnt2[t];
  int incl = v;
  int lane = t & 63, wid = t >> 6;
  for (int off = 1; off < 64; off <<= 1) {
    int o = __shfl_up(incl, off);
    if (lane >= off) incl += o;
  }
  if (lane == 63) wsum[wid] = incl;
  __syncthreads();
  if (t == 0) { int r = 0; for (int i = 0; i < 4; ++i) { int x2 = wsum[i]; wsum[i] = r; r += x2; } }
  __syncthreads();
  int excl = incl - v + wsum[wid];
  int g = (k << BSH) + t;
  if (g <= N) rowp[g] = base + excl;
  cur2[t] = excl;
  __syncthreads();
  for (int e = base + t; e < end; e += 256) {
    unsigned p = binned[e];
    int pos = atomicAdd(&cur2[p >> 24], 1);
    col[base + pos] = (int)(p & 0xFFFFFFu);
  }
}

// ---------------- layer-1 MFMA GEMM (fp32 in, fused es/ed) ----------------
template<int NO, bool F32IN>
__launch_bounds__(256)
__global__ void gemm_mfma(const void* __restrict__ Xp,
                          const unsigned short* __restrict__ Wt,
                          unsigned short* __restrict__ Y, int n,
                          const float* __restrict__ as, const float* __restrict__ ad,
                          float* __restrict__ es, float* __restrict__ ed) {
  constexpr int NT = NO / 16;
  const int wid = threadIdx.x >> 6, lane = threadIdx.x & 63;
  const int wr0 = (blockIdx.x * 4 + wid) * 32;
  if (wr0 >= n) return;
  const int cl = lane & 15, kg = lane >> 4;

  int r0c = wr0 + cl;      if (r0c > n - 1) r0c = n - 1;
  int r1c = wr0 + 16 + cl; if (r1c > n - 1) r1c = n - 1;

  f32x4 acc[2][NT] = {};
  const unsigned short* Xb = (const unsigned short*)Xp;
  const float* Xf = (const float*)Xp;

#pragma unroll
  for (int ks = 0; ks < 4; ++ks) {
    bf16x8 a0, a1;
    if constexpr (F32IN) {
      const float* p0 = Xf + (size_t)r0c * 128 + kg * 8 + ks * 32;
      const float* p1 = Xf + (size_t)r1c * 128 + kg * 8 + ks * 32;
      float4 u0 = *(const float4*)p0, u1 = *(const float4*)(p0 + 4);
      float4 w0 = *(const float4*)p1, w1 = *(const float4*)(p1 + 4);
      a0[0] = (short)f2bf(u0.x); a0[1] = (short)f2bf(u0.y); a0[2] = (short)f2bf(u0.z); a0[3] = (short)f2bf(u0.w);
      a0[4] = (short)f2bf(u1.x); a0[5] = (short)f2bf(u1.y); a0[6] = (short)f2bf(u1.z); a0[7] = (short)f2bf(u1.w);
      a1[0] = (short)f2bf(w0.x); a1[1] = (short)f2bf(w0.y); a1[2] = (short)f2bf(w0.z); a1[3] = (short)f2bf(w0.w);
      a1[4] = (short)f2bf(w1.x); a1[5] = (short)f2bf(w1.y); a1[6] = (short)f2bf(w1.z); a1[7] = (short)f2bf(w1.w);
    } else {
      a0 = *(const bf16x8*)(Xb + (size_t)r0c * 128 + kg * 8 + ks * 32);
      a1 = *(const bf16x8*)(Xb + (size_t)r1c * 128 + kg * 8 + ks * 32);
    }
#pragma unroll
    for (int t = 0; t < NT; ++t) {
      bf16x8 bb = *(const bf16x8*)(Wt + (size_t)(cl + t * 16) * 128 + kg * 8 + ks * 32);
      acc[0][t] = __builtin_amdgcn_mfma_f32_16x16x32_bf16(a0, bb, acc[0][t], 0, 0, 0);
      acc[1][t] = __builtin_amdgcn_mfma_f32_16x16x32_bf16(a1, bb, acc[1][t], 0, 0, 0);
    }
  }

  float asv[NT], adv[NT];
#pragma unroll
  for (int t = 0; t < NT; ++t) { asv[t] = as[t * 16 + cl]; adv[t] = ad[t * 16 + cl]; }

#pragma unroll
  for (int s = 0; s < 2; ++s) {
#pragma unroll
    for (int rg = 0; rg < 4; ++rg) {
      int r = wr0 + s * 16 + kg * 4 + rg;
      float ps0 = 0.f, pd0 = 0.f, ps1 = 0.f, pd1 = 0.f;
#pragma unroll
      for (int t = 0; t < NT; ++t) {
        float a = acc[s][t][rg];
        if (NO == 128 && t >= 4) { ps1 = fmaf(a, asv[t], ps1); pd1 = fmaf(a, adv[t], pd1); }
        else                     { ps0 = fmaf(a, asv[t], ps0); pd0 = fmaf(a, adv[t], pd0); }
      }
#pragma unroll
      for (int o = 8; o; o >>= 1) {
        ps0 += __shfl_xor(ps0, o); pd0 += __shfl_xor(pd0, o);
        if (NO == 128) { ps1 += __shfl_xor(ps1, o); pd1 += __shfl_xor(pd1, o); }
      }
      if (r < n) {
        if (cl == 0) {
          if (NO == 128) {
            es[(size_t)r * 2] = ps0; es[(size_t)r * 2 + 1] = ps1;
            ed[(size_t)r * 2] = pd0; ed[(size_t)r * 2 + 1] = pd1;
          } else {
            es[r] = ps0; ed[r] = pd0;
          }
        }
#pragma unroll
        for (int t = 0; t < NT; ++t)
          Y[(size_t)r * NO + t * 16 + cl] = f2bf(acc[s][t][rg]);
      }
    }
  }
}

// ---------------- fused: aggregate(layer ℓ) + BN/ReLU + GEMM(W_{ℓ+1}) + es/ed ----------------
// block = 4 waves, 64 nodes; wave handles 16 nodes (2 per round via halves), then MFMAs its 16-row Z tile.
template<int NOUT>
__launch_bounds__(256)
__global__ void agg_gemm(const unsigned short* __restrict__ xl,
                         const float* __restrict__ es, const float* __restrict__ ed,
                         const int* __restrict__ rowp, const int* __restrict__ col,
                         const float* __restrict__ bias,
                         const float* __restrict__ g, const float* __restrict__ be,
                         const float* __restrict__ m, const float* __restrict__ v,
                         const unsigned short* __restrict__ Wt,
                         const float* __restrict__ as2, const float* __restrict__ ad2,
                         unsigned short* __restrict__ Y,
                         float* __restrict__ es2, float* __restrict__ ed2,
                         int n) {
  __shared__ unsigned short Z[64][136];           // 17 KB, +8 pad vs bank conflicts
  const int wid = threadIdx.x >> 6, lane = threadIdx.x & 63;
  const int h = lane >> 5, hl = lane & 31;        // half, half-lane
  const int rl = hl >> 4, hl3 = hl & 15;          // edge-parity, 16-lane idx
  const uint4* xr = (const uint4*)xl;             // row = 16 uint4 (128 bf16)
  const int nb0 = blockIdx.x * 64;

  // ---- aggregation: 8 rounds × 2 nodes (one per half) ----
  for (int rnd = 0; rnd < 8; ++rnd) {
    int nd = nb0 + wid * 16 + rnd * 2 + h;
    bool valid = nd < n;
    int ndc = valid ? nd : n - 1;
    int beg = rowp[ndc], end = rowp[ndc + 1];
    float2 edv = *(const float2*)&ed[(size_t)ndc * 2];
    float acc[8] = {0.f, 0.f, 0.f, 0.f, 0.f, 0.f, 0.f, 0.f};
    float dl0 = 0.f, dl1 = 0.f;

    for (int cb = beg; cb < end; cb += 32) {
      int idx = cb + hl;
      int s = 0; float w0 = 0.f, w1 = 0.f;
      if (idx < end) {
        s = col[idx];
        float2 e2 = *(const float2*)&es[(size_t)s * 2];
        w0 = __expf(leaky02(e2.x + edv.x));
        w1 = __expf(leaky02(e2.y + edv.y));
      }
      dl0 += w0; dl1 += w1;
      int cend = end - cb; if (cend > 32) cend = 32;
      int i = 0;
      for (; i + 4 <= cend; i += 4) {
        int j0 = h * 32 + i + rl, j1 = h * 32 + i + 2 + rl;
        int s0 = __shfl(s, j0), s1 = __shfl(s, j1);
        float w00 = __shfl(w0, j0), w01 = __shfl(w1, j0);
        float w10 = __shfl(w0, j1), w11 = __shfl(w1, j1);
        uint4 v0 = xr[(size_t)s0 * 16 + hl3];
        uint4 v1 = xr[(size_t)s1 * 16 + hl3];
        float W0 = (hl3 < 8) ? w00 : w01;
        float W1 = (hl3 < 8) ? w10 : w11;
        acc[0] = fmaf(W0, bflo(v0.x), acc[0]); acc[1] = fmaf(W0, bfhi(v0.x), acc[1]);
        acc[2] = fmaf(W0, bflo(v0.y), acc[2]); acc[3] = fmaf(W0, bfhi(v0.y), acc[3]);
        acc[4] = fmaf(W0, bflo(v0.z), acc[4]); acc[5] = fmaf(W0, bfhi(v0.z), acc[5]);
        acc[6] = fmaf(W0, bflo(v0.w), acc[6]); acc[7] = fmaf(W0, bfhi(v0.w), acc[7]);
        acc[0] = fmaf(W1, bflo(v1.x), acc[0]); acc[1] = fmaf(W1, bfhi(v1.x), acc[1]);
        acc[2] = fmaf(W1, bflo(v1.y), acc[2]); acc[3] = fmaf(W1, bfhi(v1.y), acc[3]);
        acc[4] = fmaf(W1, bflo(v1.z), acc[4]); acc[5] = fmaf(W1, bfhi(v1.z), acc[5]);
        acc[6] = fmaf(W1, bflo(v1.w), acc[6]); acc[7] = fmaf(W1, bfhi(v1.w), acc[7]);
      }
      for (; i + 2 <= cend; i += 2) {
        int j = h * 32 + i + rl;
        int s0 = __shfl(s, j);
        float w00 = __shfl(w0, j), w01 = __shfl(w1, j);
        uint4 v0 = xr[(size_t)s0 * 16 + hl3];
        float W0 = (hl3 < 8) ? w00 : w01;
        acc[0] = fmaf(W0, bflo(v0.x), acc[0]); acc[1] = fmaf(W0, bfhi(v0.x), acc[1]);
        acc[2] = fmaf(W0, bflo(v0.y), acc[2]); acc[3] = fmaf(W0, bfhi(v0.y), acc[3]);
        acc[4] = fmaf(W0, bflo(v0.z), acc[4]); acc[5] = fmaf(W0, bfhi(v0.z), acc[5]);
        acc[6] = fmaf(W0, bflo(v0.w), acc[6]); acc[7] = fmaf(W0, bfhi(v0.w), acc[7]);
      }
      if (i < cend) {                       // 1 leftover edge: only rl==0 accumulates
        int j = h * 32 + i;
        int s0 = __shfl(s, j);
        float w00 = __shfl(w0, j), w01 = __shfl(w1, j);
        uint4 v0 = xr[(size_t)s0 * 16 + hl3];
        float W0 = (hl3 < 8) ? w00 : w01;
        if (rl) W0 = 0.f;
        acc[0] = fmaf(W0, bflo(v0.x), acc[0]); acc[1] = fmaf(W0, bfhi(v0.x), acc[1]);
        acc[2] = fmaf(W0, bflo(v0.y), acc[2]); acc[3] = fmaf(W0, bfhi(v0.y), acc[3]);
        acc[4] = fmaf(W0, bflo(v0.z), acc[4]); acc[5] = fmaf(W0, bfhi(v0.z), acc[5]);
        acc[6] = fmaf(W0, bflo(v0.w), acc[6]); acc[7] = fmaf(W0, bfhi(v0.w), acc[7]);
      }
    }
    // merge edge-parity halves (within 32-lane half)
#pragma unroll
    for (int k2 = 0; k2 < 8; ++k2) acc[k2] += __shfl_xor(acc[k2], 16);
    // den reduce over half
#pragma unroll
    for (int o = 16; o; o >>= 1) { dl0 += __shfl_xor(dl0, o); dl1 += __shfl_xor(dl1, o); }

    if (rl == 0) {
      int c0 = hl3 * 8;
      float den = (hl3 < 8) ? dl0 : dl1;
      float inv = 1.f / (den + 1e-16f);
      float4 bi0 = *(const float4*)&bias[c0], bi1 = *(const float4*)&bias[c0 + 4];
      float4 mm0 = *(const float4*)&m[c0],    mm1 = *(const float4*)&m[c0 + 4];
      float4 vv0 = *(const float4*)&v[c0],    vv1 = *(const float4*)&v[c0 + 4];
      float4 gg0 = *(const float4*)&g[c0],    gg1 = *(const float4*)&g[c0 + 4];
      float4 bb0 = *(const float4*)&be[c0],   bb1 = *(const float4*)&be[c0 + 4];
      float r0 = (acc[0] * inv + bi0.x - mm0.x) * rsqrtf(vv0.x + 1e-5f) * gg0.x + bb0.x;
      float r1 = (acc[1] * inv + bi0.y - mm0.y) * rsqrtf(vv0.y + 1e-5f) * gg0.y + bb0.y;
      float r2 = (acc[2] * inv + bi0.z - mm0.z) * rsqrtf(vv0.z + 1e-5f) * gg0.z + bb0.z;
      float r3 = (acc[3] * inv + bi0.w - mm0.w) * rsqrtf(vv0.w + 1e-5f) * gg0.w + bb0.w;
      float r4 = (acc[4] * inv + bi1.x - mm1.x) * rsqrtf(vv1.x + 1e-5f) * gg1.x + bb1.x;
      float r5 = (acc[5] * inv + bi1.y - mm1.y) * rsqrtf(vv1.y + 1e-5f) * gg1.y + bb1.y;
      float r6 = (acc[6] * inv + bi1.z - mm1.z) * rsqrtf(vv1.z + 1e-5f) * gg1.z + bb1.z;
      float r7 = (acc[7] * inv + bi1.w - mm1.w) * rsqrtf(vv1.w + 1e-5f) * gg1.w + bb1.w;
      uint4 o;
      if (valid) {
        o.x = pack2bf(fmaxf(r0, 0.f), fmaxf(r1, 0.f));
        o.y = pack2bf(fmaxf(r2, 0.f), fmaxf(r3, 0.f));
        o.z = pack2bf(fmaxf(r4, 0.f), fmaxf(r5, 0.f));
        o.w = pack2bf(fmaxf(r6, 0.f), fmaxf(r7, 0.f));
      } else {
        o.x = 0; o.y = 0; o.z = 0; o.w = 0;
      }
      *(uint4*)&Z[wid * 16 + rnd * 2 + h][c0] = o;
    }
  }
  __syncthreads();

  // ---- MFMA: Y[wave's 16 rows × NOUT] = Z @ Wt ----
  constexpr int NT = NOUT / 16;
  const int cl = lane & 15, kg = lane >> 4;
  f32x4 acc2[NT] = {};
  const unsigned short* zrow = &Z[wid * 16 + cl][0];
#pragma unroll
  for (int ks = 0; ks < 4; ++ks) {
    bf16x8 a = *(const bf16x8*)(zrow + kg * 8 + ks * 32);
#pragma unroll
    for (int t = 0; t < NT; ++t) {
      bf16x8 bb = *(const bf16x8*)(Wt + (size_t)(cl + t * 16) * 128 + kg * 8 + ks * 32);
      acc2[t] = __builtin_amdgcn_mfma_f32_16x16x32_bf16(a, bb, acc2[t], 0, 0, 0);
    }
  }
  float asv[NT], adv[NT];
#pragma unroll
  for (int t = 0; t < NT; ++t) { asv[t] = as2[t * 16 + cl]; adv[t] = ad2[t * 16 + cl]; }

#pragma unroll
  for (int rg = 0; rg < 4; ++rg) {
    int r = nb0 + wid * 16 + kg * 4 + rg;
    float ps0 = 0.f, pd0 = 0.f, ps1 = 0.f, pd1 = 0.f;
#pragma unroll
    for (int t = 0; t < NT; ++t) {
      float a = acc2[t][rg];
      if (NOUT == 128 && t >= 4) { ps1 = fmaf(a, asv[t], ps1); pd1 = fmaf(a, adv[t], pd1); }
      else                       { ps0 = fmaf(a, asv[t], ps0); pd0 = fmaf(a, adv[t], pd0); }
    }
#pragma unroll
    for (int o = 8; o; o >>= 1) {
      ps0 += __shfl_xor(ps0, o); pd0 += __shfl_xor(pd0, o);
      if (NOUT == 128) { ps1 += __shfl_xor(ps1, o); pd1 += __shfl_xor(pd1, o); }
    }
    if (r < n) {
      if (cl == 0) {
        if (NOUT == 128) {
          es2[(size_t)r * 2] = ps0; es2[(size_t)r * 2 + 1] = ps1;
          ed2[(size_t)r * 2] = pd0; ed2[(size_t)r * 2 + 1] = pd1;
        } else {
          es2[r] = ps0; ed2[r] = pd0;
        }
      }
#pragma unroll
      for (int t = 0; t < NT; ++t)
        Y[(size_t)r * NOUT + t * 16 + cl] = f2bf(acc2[t][rg]);
    }
  }
}

// ---------------- final aggregation H=1: lane-eighths, uint4 rows ----------------
__launch_bounds__(256)
__global__ void aggregate1(const unsigned short* __restrict__ xl, const float* __restrict__ es,
                           const float* __restrict__ ed, const int* __restrict__ rowp,
                           const int* __restrict__ col, const float* __restrict__ bias,
                           const float* __restrict__ g, const float* __restrict__ be,
                           const float* __restrict__ m, const float* __restrict__ v,
                           float* __restrict__ out, int n) {
  int node = (blockIdx.x * blockDim.x + threadIdx.x) >> 6;
  int lane = threadIdx.x & 63;
  if (node >= n) return;
  const uint4* xr = (const uint4*)xl;       // row = 8 uint4 (64 bf16)
  int beg = rowp[node], end = rowp[node + 1];
  float edv = ed[node];
  const int g8 = lane >> 3, hl = lane & 7;

  float acc[8] = {0.f, 0.f, 0.f, 0.f, 0.f, 0.f, 0.f, 0.f};
  float dl = 0.f;

  for (int cb = beg; cb < end; cb += 64) {
    int idx = cb + lane;
    int s = 0; float w = 0.f;
    if (idx < end) {
      s = col[idx];
      w = __expf(leaky02(es[s] + edv));
    }
    dl += w;
    int cend = end - cb; if (cend > 64) cend = 64;
    int i = 0;
    for (; i + 16 <= cend; i += 16) {
      int j0 = i + g8, j1 = i + 8 + g8;
      int s0 = __shfl(s, j0), s1 = __shfl(s, j1);
      uint4 v0 = xr[(size_t)s0 * 8 + hl];
      uint4 v1 = xr[(size_t)s1 * 8 + hl];
      float W0 = __shfl(w, j0), W1 = __shfl(w, j1);
      acc[0] = fmaf(W0, bflo(v0.x), acc[0]); acc[1] = fmaf(W0, bfhi(v0.x), acc[1]);
      acc[2] = fmaf(W0, bflo(v0.y), acc[2]); acc[3] = fmaf(W0, bfhi(v0.y), acc[3]);
      acc[4] = fmaf(W0, bflo(v0.z), acc[4]); acc[5] = fmaf(W0, bfhi(v0.z), acc[5]);
      acc[6] = fmaf(W0, bflo(v0.w), acc[6]); acc[7] = fmaf(W0, bfhi(v0.w), acc[7]);
      acc[0] = fmaf(W1, bflo(v1.x), acc[0]); acc[1] = fmaf(W1, bfhi(v1.x), acc[1]);
      acc[2] = fmaf(W1, bflo(v1.y), acc[2]); acc[3] = fmaf(W1, bfhi(v1.y), acc[3]);
      acc[4] = fmaf(W1, bflo(v1.z), acc[4]); acc[5] = fmaf(W1, bfhi(v1.z), acc[5]);
      acc[6] = fmaf(W1, bflo(v1.w), acc[6]); acc[7] = fmaf(W1, bfhi(v1.w), acc[7]);
    }
    for (; i < cend; i += 8) {
      int j = i + g8;
      int s0 = __shfl(s, j);
      uint4 v0 = xr[(size_t)s0 * 8 + hl];
      float W0 = __shfl(w, j);
      acc[0] = fmaf(W0, bflo(v0.x), acc[0]); acc[1] = fmaf(W0, bfhi(v0.x), acc[1]);
      acc[2] = fmaf(W0, bflo(v0.y), acc[2]); acc[3] = fmaf(W0, bfhi(v0.y), acc[3]);
      acc[4] = fmaf(W0, bflo(v0.z), acc[4]); acc[5] = fmaf(W0, bfhi(v0.z), acc[5]);
      acc[6] = fmaf(W0, bflo(v0.w), acc[6]); acc[7] = fmaf(W0, bfhi(v0.w), acc[7]);
    }
  }

#pragma unroll
  for (int k2 = 0; k2 < 8; ++k2) {
    acc[k2] += __shfl_xor(acc[k2], 8);
    acc[k2] += __shfl_xor(acc[k2], 16);
    acc[k2] += __shfl_xor(acc[k2], 32);
  }
#pragma unroll
  for (int o = 32; o; o >>= 1) dl += __shfl_xor(dl, o);

  if (lane < 8) {
    int c0 = hl * 8;
    float inv = 1.f / (dl + 1e-16f);
    float4 bi0 = *(const float4*)&bias[c0], bi1 = *(const float4*)&bias[c0 + 4];
    float4 mm0 = *(const float4*)&m[c0],    mm1 = *(const float4*)&m[c0 + 4];
    float4 vv0 = *(const float4*)&v[c0],    vv1 = *(const float4*)&v[c0 + 4];
    float4 gg0 = *(const float4*)&g[c0],    gg1 = *(const float4*)&g[c0 + 4];
    float4 bb0 = *(const float4*)&be[c0],   bb1 = *(const float4*)&be[c0 + 4];
    float4 ra, rb;
    ra.x = (acc[0] * inv + bi0.x - mm0.x) * rsqrtf(vv0.x + 1e-5f) * gg0.x + bb0.x;
    ra.y = (acc[1] * inv + bi0.y - mm0.y) * rsqrtf(vv0.y + 1e-5f) * gg0.y + bb0.y;
    ra.z = (acc[2] * inv + bi0.z - mm0.z) * rsqrtf(vv0.z + 1e-5f) * gg0.z + bb0.z;
    ra.w = (acc[3] * inv + bi0.w - mm0.w) * rsqrtf(vv0.w + 1e-5f) * gg0.w + bb0.w;
    rb.x = (acc[4] * inv + bi1.x - mm1.x) * rsqrtf(vv1.x + 1e-5f) * gg1.x + bb1.x;
    rb.y = (acc[5] * inv + bi1.y - mm1.y) * rsqrtf(vv1.y + 1e-5f) * gg1.y + bb1.y;
    rb.z = (acc[6] * inv + bi1.z - mm1.z) * rsqrtf(vv1.z + 1e-5f) * gg1.z + bb1.z;
    rb.w = (acc[7] * inv + bi1.w - mm1.w) * rsqrtf(vv1.w + 1e-5f) * gg1.w + bb1.w;
    float4* op = (float4*)(out + (size_t)node * 64 + c0);
    op[0] = ra; op[1] = rb;
  }
}

extern "C" void kernel_launch(void* const* d_in, const int* in_sizes, int n_in,
                              void* d_out, int out_size, void* d_ws, size_t ws_size,
                              hipStream_t stream) {
  const float* x   = (const float*)d_in[0];
  const int*   ei  = (const int*)d_in[1];
  const float* w1  = (const float*)d_in[2];
  const float* as1 = (const float*)d_in[3];
  const float* ad1 = (const float*)d_in[4];
  const float* b1  = (const float*)d_in[5];
  const float* w2  = (const float*)d_in[6];
  const float* as2 = (const float*)d_in[7];
  const float* ad2 = (const float*)d_in[8];
  const float* b2  = (const float*)d_in[9];
  const float* w3  = (const float*)d_in[10];
  const float* as3 = (const float*)d_in[11];
  const float* ad3 = (const float*)d_in[12];
  const float* b3  = (const float*)d_in[13];
  const float* g1  = (const float*)d_in[14];
  const float* be1 = (const float*)d_in[15];
  const float* m1  = (const float*)d_in[16];
  const float* v1  = (const float*)d_in[17];
  const float* g2  = (const float*)d_in[18];
  const float* be2 = (const float*)d_in[19];
  const float* m2  = (const float*)d_in[20];
  const float* v2  = (const float*)d_in[21];
  const float* g3  = (const float*)d_in[22];
  const float* be3 = (const float*)d_in[23];
  const float* m3  = (const float*)d_in[24];
  const float* v3  = (const float*)d_in[25];

  const int N = in_sizes[0] / 128;
  const int E = in_sizes[1] / 2;
  const int Etot = E + N;                   // self-loops folded in
  const int* srcp = ei;
  const int* dstp = ei + E;
  const int NB = (N + 255) >> BSH;
  const int echunk = (E + NBLK - 1) / NBLK;
  const int nchunk = (N + NBLK - 1) / NBLK;

  size_t off = 0;
  auto carve = [&](size_t bytes) {
    void* p = (char*)d_ws + off;
    off += (bytes + 255) & ~(size_t)255;
    return p;
  };
  unsigned short* xl1 = (unsigned short*)carve((size_t)N * 128 * 2);
  unsigned short* xl2 = (unsigned short*)carve((size_t)N * 128 * 2);
  float* es1 = (float*)carve((size_t)N * 2 * 4);
  float* ed1 = (float*)carve((size_t)N * 2 * 4);
  float* es2 = (float*)carve((size_t)N * 2 * 4);
  float* ed2 = (float*)carve((size_t)N * 2 * 4);
  float* es3 = (float*)carve((size_t)N * 4);
  float* ed3 = (float*)carve((size_t)N * 4);
  int*   rowp = (int*)carve((size_t)(N + 1) * 4);
  int*   col  = (int*)carve((size_t)Etot * 4);
  // xl3 aliases binned (binned dead before xl3 is written)
  size_t u = (size_t)N * 64 * 2; size_t ub = (size_t)Etot * 4;
  unsigned short* xl3 = (unsigned short*)carve(u > ub ? u : ub);
  unsigned* binned = (unsigned*)xl3;
  int* T = (int*)carve(512 * 4);
  int* B = (int*)carve(513 * 4);
  int* C = (int*)carve(512 * 4);
  unsigned short* Wt1 = (unsigned short*)carve(128 * 128 * 2);
  unsigned short* Wt2 = (unsigned short*)carve(128 * 128 * 2);
  unsigned short* Wt3 = (unsigned short*)carve(128 * 64 * 2);
  (void)ws_size; (void)n_in; (void)out_size;

  // CSR build
  hipMemsetAsync(T, 0, NB * 4, stream);
  bucket_hist<<<NBLK + 160, 256, 0, stream>>>(dstp, T, E, N, NB, echunk, nchunk,
                                              w1, w2, w3, Wt1, Wt2, Wt3);
  scan_small<<<1, 512, 0, stream>>>(T, B, C, NB);
  bucketB2<<<NBLK, 256, 0, stream>>>(srcp, dstp, C, binned, E, N, NB, echunk, nchunk);
  bucketC2<<<NB, 256, 0, stream>>>(binned, B, rowp, col, N);

  const int gemm_grid = (N + 127) / 128;
  const int fuse_grid = (N + 63) / 64;
  const int agg_grid  = (N + 3) / 4;

  // layer 1 GEMM (fp32 input, fused bf16 convert + es1/ed1)
  gemm_mfma<128, true><<<gemm_grid, 256, 0, stream>>>(x, Wt1, xl1, N, as1, ad1, es1, ed1);
  // layer-1 aggregate + BN1/ReLU + GEMM W2 + es2/ed2
  agg_gemm<128><<<fuse_grid, 256, 0, stream>>>(xl1, es1, ed1, rowp, col, b1, g1, be1, m1, v1,
                                               Wt2, as2, ad2, xl2, es2, ed2, N);
  // layer-2 aggregate + BN2/ReLU + GEMM W3 + es3/ed3
  agg_gemm<64><<<fuse_grid, 256, 0, stream>>>(xl2, es2, ed2, rowp, col, b2, g2, be2, m2, v2,
                                              Wt3, as3, ad3, xl3, es3, ed3, N);
  // layer-3 aggregate + BN3 -> d_out
  aggregate1<<<agg_grid, 256, 0, stream>>>(xl3, es3, ed3, rowp, col, b3, g3, be3, m3, v3,
                                           (float*)d_out, N);
}

// Round 7
// 348.283 us; speedup vs baseline: 1.0442x; 1.0442x over previous
//
#include <hip/hip_runtime.h>
#include <hip/hip_bf16.h>
#include <cstdint>
#include <cstddef>

#define NBLK 512          // binning blocks
#define BSH 8             // bucket shift: 256 nodes per bucket

typedef short bf16x8 __attribute__((ext_vector_type(8)));
typedef float f32x4 __attribute__((ext_vector_type(4)));

__device__ __forceinline__ float leaky02(float x) { return x > 0.f ? x : 0.2f * x; }
__device__ __forceinline__ float bflo(unsigned u) { return __uint_as_float(u << 16); }
__device__ __forceinline__ float bfhi(unsigned u) { return __uint_as_float(u & 0xFFFF0000u); }
__device__ __forceinline__ unsigned short f2bf(float f) {
  __hip_bfloat16 h = __float2bfloat16(f);
  return *(unsigned short*)&h;
}
__device__ __forceinline__ unsigned pack2bf(float a, float b) {
  return (unsigned)f2bf(a) | ((unsigned)f2bf(b) << 16);
}

// ---------------- CSR build: hist (+ fused weight transpose) ----------------
__global__ void bucket_hist(const int* __restrict__ dst, int* __restrict__ T,
                            int E, int N, int NB, int echunk, int nchunk,
                            const float* __restrict__ w1, const float* __restrict__ w2,
                            const float* __restrict__ w3,
                            unsigned short* __restrict__ t1, unsigned short* __restrict__ t2,
                            unsigned short* __restrict__ t3) {
  int b = blockIdx.x, t = threadIdx.x;
  if (b >= NBLK) {          // prep_w part: W[128][NO] fp32 -> Wt[NO][128] bf16
    int bb = b - NBLK;
    const float* W; unsigned short* Tw; int NO; int e;
    if (bb < 64)      { W = w1; Tw = t1; NO = 128; e = bb * 256 + t; }
    else if (bb < 128){ W = w2; Tw = t2; NO = 128; e = (bb - 64) * 256 + t; }
    else              { W = w3; Tw = t3; NO = 64;  e = (bb - 128) * 256 + t; }
    int c = e >> 7, k = e & 127;
    Tw[c * 128 + k] = f2bf(W[k * NO + c]);
    return;
  }
  __shared__ int hist[512];
  hist[t] = 0; hist[t + 256] = 0;
  __syncthreads();
  int e0 = b * echunk, e1 = min(E, e0 + echunk);
  for (int e = e0 + t; e < e1; e += 256) atomicAdd(&hist[dst[e] >> BSH], 1);
  int n0 = b * nchunk, n1 = min(N, n0 + nchunk);
  for (int nn = n0 + t; nn < n1; nn += 256) atomicAdd(&hist[nn >> BSH], 1);
  __syncthreads();
  for (int k = t; k < NB; k += 256) if (hist[k]) atomicAdd(&T[k], hist[k]);
}

// 1-block scan of bucket totals -> bases B[0..NB] + cursors C[0..NB)
__global__ void scan_small(const int* __restrict__ T, int* __restrict__ B,
                           int* __restrict__ C, int NB) {
  __shared__ int wsum[8];
  int t = threadIdx.x;
  int val = (t < NB) ? T[t] : 0;
  int lane = t & 63, wid = t >> 6;
  int incl = val;
  for (int off = 1; off < 64; off <<= 1) {
    int o = __shfl_up(incl, off);
    if (lane >= off) incl += o;
  }
  if (lane == 63) wsum[wid] = incl;
  __syncthreads();
  if (t == 0) { int r = 0; for (int i = 0; i < 8; ++i) { int x = wsum[i]; wsum[i] = r; r += x; } }
  __syncthreads();
  int excl = incl - val + wsum[wid];
  if (t <= NB) B[t] = excl;
  if (t < NB) C[t] = excl;
}

// count chunk -> claim ranges -> scatter payloads (src | localdst<<24)
__global__ void bucketB2(const int* __restrict__ src, const int* __restrict__ dst,
                         int* __restrict__ C, unsigned* __restrict__ binned,
                         int E, int N, int NB, int echunk, int nchunk) {
  __shared__ int hist[512];
  __shared__ int cur[512];
  int b = blockIdx.x, t = threadIdx.x;
  hist[t] = 0; hist[t + 256] = 0;
  __syncthreads();
  int e0 = b * echunk, e1 = min(E, e0 + echunk);
  for (int e = e0 + t; e < e1; e += 256) atomicAdd(&hist[dst[e] >> BSH], 1);
  int n0 = b * nchunk, n1 = min(N, n0 + nchunk);
  for (int nn = n0 + t; nn < n1; nn += 256) atomicAdd(&hist[nn >> BSH], 1);
  __syncthreads();
  for (int k = t; k < 512; k += 256) {
    int c = hist[k];
    cur[k] = c ? atomicAdd(&C[k], c) : 0;
  }
  __syncthreads();
  for (int e = e0 + t; e < e1; e += 256) {
    int d = dst[e];
    int k = d >> BSH;
    int pos = atomicAdd(&cur[k], 1);
    binned[pos] = (unsigned)src[e] | ((unsigned)(d & 255) << 24);
  }
  for (int nn = n0 + t; nn < n1; nn += 256) {
    int k = nn >> BSH;
    int pos = atomicAdd(&cur[k], 1);
    binned[pos] = (unsigned)nn | ((unsigned)(nn & 255) << 24);
  }
}

// per-bucket counting sort -> rowp + col
__global__ void bucketC2(const unsigned* __restrict__ binned, const int* __restrict__ B,
                         int* __restrict__ rowp, int* __restrict__ col, int N) {
  __shared__ int cnt2[256];
  __shared__ int cur2[256];
  __shared__ int wsum[4];
  int k = blockIdx.x, t = threadIdx.x;
  int base = B[k];
  int end  = B[k + 1];
  cnt2[t] = 0;
  __syncthreads();
  for (int e = base + t; e < end; e += 256) atomicAdd(&cnt2[binned[e] >> 24], 1);
  __syncthreads();
  int v = cnt2[t];
  int incl = v;
  int lane = t & 63, wid = t >> 6;
  for (int off = 1; off < 64; off <<= 1) {
    int o = __shfl_up(incl, off);
    if (lane >= off) incl += o;
  }
  if (lane == 63) wsum[wid] = incl;
  __syncthreads();
  if (t == 0) { int r = 0; for (int i = 0; i < 4; ++i) { int x2 = wsum[i]; wsum[i] = r; r += x2; } }
  __syncthreads();
  int excl = incl - v + wsum[wid];
  int g = (k << BSH) + t;
  if (g <= N) rowp[g] = base + excl;
  cur2[t] = excl;
  __syncthreads();
  for (int e = base + t; e < end; e += 256) {
    unsigned p = binned[e];
    int pos = atomicAdd(&cur2[p >> 24], 1);
    col[base + pos] = (int)(p & 0xFFFFFFu);
  }
}

// ---------------- MFMA GEMM: Y[n,NO](bf16) = X[n,128] @ W, fused es/ed ----------------
template<int NO, bool F32IN>
__launch_bounds__(256)
__global__ void gemm_mfma(const void* __restrict__ Xp,
                          const unsigned short* __restrict__ Wt,
                          unsigned short* __restrict__ Y, int n,
                          const float* __restrict__ as, const float* __restrict__ ad,
                          float* __restrict__ es, float* __restrict__ ed) {
  constexpr int NT = NO / 16;
  const int wid = threadIdx.x >> 6, lane = threadIdx.x & 63;
  const int wr0 = (blockIdx.x * 4 + wid) * 32;
  if (wr0 >= n) return;
  const int cl = lane & 15, kg = lane >> 4;

  int r0c = wr0 + cl;      if (r0c > n - 1) r0c = n - 1;
  int r1c = wr0 + 16 + cl; if (r1c > n - 1) r1c = n - 1;

  f32x4 acc[2][NT] = {};
  const unsigned short* Xb = (const unsigned short*)Xp;
  const float* Xf = (const float*)Xp;

#pragma unroll
  for (int ks = 0; ks < 4; ++ks) {
    bf16x8 a0, a1;
    if constexpr (F32IN) {
      const float* p0 = Xf + (size_t)r0c * 128 + kg * 8 + ks * 32;
      const float* p1 = Xf + (size_t)r1c * 128 + kg * 8 + ks * 32;
      float4 u0 = *(const float4*)p0, u1 = *(const float4*)(p0 + 4);
      float4 w0 = *(const float4*)p1, w1 = *(const float4*)(p1 + 4);
      a0[0] = (short)f2bf(u0.x); a0[1] = (short)f2bf(u0.y); a0[2] = (short)f2bf(u0.z); a0[3] = (short)f2bf(u0.w);
      a0[4] = (short)f2bf(u1.x); a0[5] = (short)f2bf(u1.y); a0[6] = (short)f2bf(u1.z); a0[7] = (short)f2bf(u1.w);
      a1[0] = (short)f2bf(w0.x); a1[1] = (short)f2bf(w0.y); a1[2] = (short)f2bf(w0.z); a1[3] = (short)f2bf(w0.w);
      a1[4] = (short)f2bf(w1.x); a1[5] = (short)f2bf(w1.y); a1[6] = (short)f2bf(w1.z); a1[7] = (short)f2bf(w1.w);
    } else {
      a0 = *(const bf16x8*)(Xb + (size_t)r0c * 128 + kg * 8 + ks * 32);
      a1 = *(const bf16x8*)(Xb + (size_t)r1c * 128 + kg * 8 + ks * 32);
    }
#pragma unroll
    for (int t = 0; t < NT; ++t) {
      bf16x8 bb = *(const bf16x8*)(Wt + (size_t)(cl + t * 16) * 128 + kg * 8 + ks * 32);
      acc[0][t] = __builtin_amdgcn_mfma_f32_16x16x32_bf16(a0, bb, acc[0][t], 0, 0, 0);
      acc[1][t] = __builtin_amdgcn_mfma_f32_16x16x32_bf16(a1, bb, acc[1][t], 0, 0, 0);
    }
  }

  float asv[NT], adv[NT];
#pragma unroll
  for (int t = 0; t < NT; ++t) { asv[t] = as[t * 16 + cl]; adv[t] = ad[t * 16 + cl]; }

#pragma unroll
  for (int s = 0; s < 2; ++s) {
#pragma unroll
    for (int rg = 0; rg < 4; ++rg) {
      int r = wr0 + s * 16 + kg * 4 + rg;
      float ps0 = 0.f, pd0 = 0.f, ps1 = 0.f, pd1 = 0.f;
#pragma unroll
      for (int t = 0; t < NT; ++t) {
        float a = acc[s][t][rg];
        if (NO == 128 && t >= 4) { ps1 = fmaf(a, asv[t], ps1); pd1 = fmaf(a, adv[t], pd1); }
        else                     { ps0 = fmaf(a, asv[t], ps0); pd0 = fmaf(a, adv[t], pd0); }
      }
#pragma unroll
      for (int o = 8; o; o >>= 1) {
        ps0 += __shfl_xor(ps0, o); pd0 += __shfl_xor(pd0, o);
        if (NO == 128) { ps1 += __shfl_xor(ps1, o); pd1 += __shfl_xor(pd1, o); }
      }
      if (r < n) {
        if (cl == 0) {
          if (NO == 128) {
            es[(size_t)r * 2] = ps0; es[(size_t)r * 2 + 1] = ps1;
            ed[(size_t)r * 2] = pd0; ed[(size_t)r * 2 + 1] = pd1;
          } else {
            es[r] = ps0; ed[r] = pd0;
          }
        }
#pragma unroll
        for (int t = 0; t < NT; ++t)
          Y[(size_t)r * NO + t * 16 + cl] = f2bf(acc[s][t][rg]);
      }
    }
  }
}

// ---------------- aggregation H=2: lane-quarters, uint4 rows (4 edges/load) ----------------
__launch_bounds__(256)
__global__ void aggregate2(const unsigned short* __restrict__ xl, const float* __restrict__ es,
                           const float* __restrict__ ed, const int* __restrict__ rowp,
                           const int* __restrict__ col, const float* __restrict__ bias,
                           const float* __restrict__ g, const float* __restrict__ be,
                           const float* __restrict__ m, const float* __restrict__ v,
                           uint4* __restrict__ out, int n) {
  int node = (blockIdx.x * blockDim.x + threadIdx.x) >> 6;
  int lane = threadIdx.x & 63;
  if (node >= n) return;
  const uint4* xr = (const uint4*)xl;       // row = 16 uint4 (128 bf16)
  int beg = rowp[node], end = rowp[node + 1];
  float2 edv = *(const float2*)&ed[(size_t)node * 2];
  const int q = lane >> 4, hl = lane & 15;

  float acc[8] = {0.f, 0.f, 0.f, 0.f, 0.f, 0.f, 0.f, 0.f};
  float dl0 = 0.f, dl1 = 0.f;

  for (int cb = beg; cb < end; cb += 64) {
    int idx = cb + lane;
    int s = 0; float w0 = 0.f, w1 = 0.f;
    if (idx < end) {
      s = col[idx];
      float2 e2 = *(const float2*)&es[(size_t)s * 2];
      w0 = __expf(leaky02(e2.x + edv.x));
      w1 = __expf(leaky02(e2.y + edv.y));
    }
    dl0 += w0; dl1 += w1;
    int cend = end - cb; if (cend > 64) cend = 64;
    int i = 0;
    for (; i + 8 <= cend; i += 8) {
      int j0 = i + q, j1 = i + 4 + q;
      int s0 = __shfl(s, j0), s1 = __shfl(s, j1);
      uint4 v0 = xr[(size_t)s0 * 16 + hl];
      uint4 v1 = xr[(size_t)s1 * 16 + hl];
      float w00 = __shfl(w0, j0), w01 = __shfl(w1, j0);
      float w10 = __shfl(w0, j1), w11 = __shfl(w1, j1);
      float W0 = (hl < 8) ? w00 : w01;
      float W1 = (hl < 8) ? w10 : w11;
      acc[0] = fmaf(W0, bflo(v0.x), acc[0]); acc[1] = fmaf(W0, bfhi(v0.x), acc[1]);
      acc[2] = fmaf(W0, bflo(v0.y), acc[2]); acc[3] = fmaf(W0, bfhi(v0.y), acc[3]);
      acc[4] = fmaf(W0, bflo(v0.z), acc[4]); acc[5] = fmaf(W0, bfhi(v0.z), acc[5]);
      acc[6] = fmaf(W0, bflo(v0.w), acc[6]); acc[7] = fmaf(W0, bfhi(v0.w), acc[7]);
      acc[0] = fmaf(W1, bflo(v1.x), acc[0]); acc[1] = fmaf(W1, bfhi(v1.x), acc[1]);
      acc[2] = fmaf(W1, bflo(v1.y), acc[2]); acc[3] = fmaf(W1, bfhi(v1.y), acc[3]);
      acc[4] = fmaf(W1, bflo(v1.z), acc[4]); acc[5] = fmaf(W1, bfhi(v1.z), acc[5]);
      acc[6] = fmaf(W1, bflo(v1.w), acc[6]); acc[7] = fmaf(W1, bfhi(v1.w), acc[7]);
    }
    for (; i < cend; i += 4) {
      int j = i + q;
      int s0 = __shfl(s, j);
      uint4 v0 = xr[(size_t)s0 * 16 + hl];
      float w00 = __shfl(w0, j), w01 = __shfl(w1, j);
      float W0 = (hl < 8) ? w00 : w01;
      acc[0] = fmaf(W0, bflo(v0.x), acc[0]); acc[1] = fmaf(W0, bfhi(v0.x), acc[1]);
      acc[2] = fmaf(W0, bflo(v0.y), acc[2]); acc[3] = fmaf(W0, bfhi(v0.y), acc[3]);
      acc[4] = fmaf(W0, bflo(v0.z), acc[4]); acc[5] = fmaf(W0, bfhi(v0.z), acc[5]);
      acc[6] = fmaf(W0, bflo(v0.w), acc[6]); acc[7] = fmaf(W0, bfhi(v0.w), acc[7]);
    }
  }

#pragma unroll
  for (int k2 = 0; k2 < 8; ++k2) {
    acc[k2] += __shfl_xor(acc[k2], 16);
    acc[k2] += __shfl_xor(acc[k2], 32);
  }
#pragma unroll
  for (int o = 32; o; o >>= 1) { dl0 += __shfl_xor(dl0, o); dl1 += __shfl_xor(dl1, o); }

  if (q == 0) {
    int c0 = hl * 8;
    float den = (hl < 8) ? dl0 : dl1;
    float inv = 1.f / (den + 1e-16f);
    float4 bi0 = *(const float4*)&bias[c0], bi1 = *(const float4*)&bias[c0 + 4];
    float4 mm0 = *(const float4*)&m[c0],    mm1 = *(const float4*)&m[c0 + 4];
    float4 vv0 = *(const float4*)&v[c0],    vv1 = *(const float4*)&v[c0 + 4];
    float4 gg0 = *(const float4*)&g[c0],    gg1 = *(const float4*)&g[c0 + 4];
    float4 bb0 = *(const float4*)&be[c0],   bb1 = *(const float4*)&be[c0 + 4];
    float r0 = (acc[0] * inv + bi0.x - mm0.x) * rsqrtf(vv0.x + 1e-5f) * gg0.x + bb0.x;
    float r1 = (acc[1] * inv + bi0.y - mm0.y) * rsqrtf(vv0.y + 1e-5f) * gg0.y + bb0.y;
    float r2 = (acc[2] * inv + bi0.z - mm0.z) * rsqrtf(vv0.z + 1e-5f) * gg0.z + bb0.z;
    float r3 = (acc[3] * inv + bi0.w - mm0.w) * rsqrtf(vv0.w + 1e-5f) * gg0.w + bb0.w;
    float r4 = (acc[4] * inv + bi1.x - mm1.x) * rsqrtf(vv1.x + 1e-5f) * gg1.x + bb1.x;
    float r5 = (acc[5] * inv + bi1.y - mm1.y) * rsqrtf(vv1.y + 1e-5f) * gg1.y + bb1.y;
    float r6 = (acc[6] * inv + bi1.z - mm1.z) * rsqrtf(vv1.z + 1e-5f) * gg1.z + bb1.z;
    float r7 = (acc[7] * inv + bi1.w - mm1.w) * rsqrtf(vv1.w + 1e-5f) * gg1.w + bb1.w;
    uint4 o;
    o.x = pack2bf(fmaxf(r0, 0.f), fmaxf(r1, 0.f));
    o.y = pack2bf(fmaxf(r2, 0.f), fmaxf(r3, 0.f));
    o.z = pack2bf(fmaxf(r4, 0.f), fmaxf(r5, 0.f));
    o.w = pack2bf(fmaxf(r6, 0.f), fmaxf(r7, 0.f));
    out[(size_t)node * 16 + hl] = o;
  }
}

// ---------------- aggregation H=1: lane-eighths, uint4 rows (8 edges/load) ----------------
__launch_bounds__(256)
__global__ void aggregate1(const unsigned short* __restrict__ xl, const float* __restrict__ es,
                           const float* __restrict__ ed, const int* __restrict__ rowp,
                           const int* __restrict__ col, const float* __restrict__ bias,
                           const float* __restrict__ g, const float* __restrict__ be,
                           const float* __restrict__ m, const float* __restrict__ v,
                           float* __restrict__ out, int n) {
  int node = (blockIdx.x * blockDim.x + threadIdx.x) >> 6;
  int lane = threadIdx.x & 63;
  if (node >= n) return;
  const uint4* xr = (const uint4*)xl;       // row = 8 uint4 (64 bf16)
  int beg = rowp[node], end = rowp[node + 1];
  float edv = ed[node];
  const int g8 = lane >> 3, hl = lane & 7;

  float acc[8] = {0.f, 0.f, 0.f, 0.f, 0.f, 0.f, 0.f, 0.f};
  float dl = 0.f;

  for (int cb = beg; cb < end; cb += 64) {
    int idx = cb + lane;
    int s = 0; float w = 0.f;
    if (idx < end) {
      s = col[idx];
      w = __expf(leaky02(es[s] + edv));
    }
    dl += w;
    int cend = end - cb; if (cend > 64) cend = 64;
    int i = 0;
    for (; i + 16 <= cend; i += 16) {
      int j0 = i + g8, j1 = i + 8 + g8;
      int s0 = __shfl(s, j0), s1 = __shfl(s, j1);
      uint4 v0 = xr[(size_t)s0 * 8 + hl];
      uint4 v1 = xr[(size_t)s1 * 8 + hl];
      float W0 = __shfl(w, j0), W1 = __shfl(w, j1);
      acc[0] = fmaf(W0, bflo(v0.x), acc[0]); acc[1] = fmaf(W0, bfhi(v0.x), acc[1]);
      acc[2] = fmaf(W0, bflo(v0.y), acc[2]); acc[3] = fmaf(W0, bfhi(v0.y), acc[3]);
      acc[4] = fmaf(W0, bflo(v0.z), acc[4]); acc[5] = fmaf(W0, bfhi(v0.z), acc[5]);
      acc[6] = fmaf(W0, bflo(v0.w), acc[6]); acc[7] = fmaf(W0, bfhi(v0.w), acc[7]);
      acc[0] = fmaf(W1, bflo(v1.x), acc[0]); acc[1] = fmaf(W1, bfhi(v1.x), acc[1]);
      acc[2] = fmaf(W1, bflo(v1.y), acc[2]); acc[3] = fmaf(W1, bfhi(v1.y), acc[3]);
      acc[4] = fmaf(W1, bflo(v1.z), acc[4]); acc[5] = fmaf(W1, bfhi(v1.z), acc[5]);
      acc[6] = fmaf(W1, bflo(v1.w), acc[6]); acc[7] = fmaf(W1, bfhi(v1.w), acc[7]);
    }
    for (; i < cend; i += 8) {
      int j = i + g8;
      int s0 = __shfl(s, j);
      uint4 v0 = xr[(size_t)s0 * 8 + hl];
      float W0 = __shfl(w, j);
      acc[0] = fmaf(W0, bflo(v0.x), acc[0]); acc[1] = fmaf(W0, bfhi(v0.x), acc[1]);
      acc[2] = fmaf(W0, bflo(v0.y), acc[2]); acc[3] = fmaf(W0, bfhi(v0.y), acc[3]);
      acc[4] = fmaf(W0, bflo(v0.z), acc[4]); acc[5] = fmaf(W0, bfhi(v0.z), acc[5]);
      acc[6] = fmaf(W0, bflo(v0.w), acc[6]); acc[7] = fmaf(W0, bfhi(v0.w), acc[7]);
    }
  }

#pragma unroll
  for (int k2 = 0; k2 < 8; ++k2) {
    acc[k2] += __shfl_xor(acc[k2], 8);
    acc[k2] += __shfl_xor(acc[k2], 16);
    acc[k2] += __shfl_xor(acc[k2], 32);
  }
#pragma unroll
  for (int o = 32; o; o >>= 1) dl += __shfl_xor(dl, o);

  if (lane < 8) {
    int c0 = hl * 8;
    float inv = 1.f / (dl + 1e-16f);
    float4 bi0 = *(const float4*)&bias[c0], bi1 = *(const float4*)&bias[c0 + 4];
    float4 mm0 = *(const float4*)&m[c0],    mm1 = *(const float4*)&m[c0 + 4];
    float4 vv0 = *(const float4*)&v[c0],    vv1 = *(const float4*)&v[c0 + 4];
    float4 gg0 = *(const float4*)&g[c0],    gg1 = *(const float4*)&g[c0 + 4];
    float4 bb0 = *(const float4*)&be[c0],   bb1 = *(const float4*)&be[c0 + 4];
    float4 ra, rb;
    ra.x = (acc[0] * inv + bi0.x - mm0.x) * rsqrtf(vv0.x + 1e-5f) * gg0.x + bb0.x;
    ra.y = (acc[1] * inv + bi0.y - mm0.y) * rsqrtf(vv0.y + 1e-5f) * gg0.y + bb0.y;
    ra.z = (acc[2] * inv + bi0.z - mm0.z) * rsqrtf(vv0.z + 1e-5f) * gg0.z + bb0.z;
    ra.w = (acc[3] * inv + bi0.w - mm0.w) * rsqrtf(vv0.w + 1e-5f) * gg0.w + bb0.w;
    rb.x = (acc[4] * inv + bi1.x - mm1.x) * rsqrtf(vv1.x + 1e-5f) * gg1.x + bb1.x;
    rb.y = (acc[5] * inv + bi1.y - mm1.y) * rsqrtf(vv1.y + 1e-5f) * gg1.y + bb1.y;
    rb.z = (acc[6] * inv + bi1.z - mm1.z) * rsqrtf(vv1.z + 1e-5f) * gg1.z + bb1.z;
    rb.w = (acc[7] * inv + bi1.w - mm1.w) * rsqrtf(vv1.w + 1e-5f) * gg1.w + bb1.w;
    float4* op = (float4*)(out + (size_t)node * 64 + c0);
    op[0] = ra; op[1] = rb;
  }
}

extern "C" void kernel_launch(void* const* d_in, const int* in_sizes, int n_in,
                              void* d_out, int out_size, void* d_ws, size_t ws_size,
                              hipStream_t stream) {
  const float* x   = (const float*)d_in[0];
  const int*   ei  = (const int*)d_in[1];
  const float* w1  = (const float*)d_in[2];
  const float* as1 = (const float*)d_in[3];
  const float* ad1 = (const float*)d_in[4];
  const float* b1  = (const float*)d_in[5];
  const float* w2  = (const float*)d_in[6];
  const float* as2 = (const float*)d_in[7];
  const float* ad2 = (const float*)d_in[8];
  const float* b2  = (const float*)d_in[9];
  const float* w3  = (const float*)d_in[10];
  const float* as3 = (const float*)d_in[11];
  const float* ad3 = (const float*)d_in[12];
  const float* b3  = (const float*)d_in[13];
  const float* g1  = (const float*)d_in[14];
  const float* be1 = (const float*)d_in[15];
  const float* m1  = (const float*)d_in[16];
  const float* v1  = (const float*)d_in[17];
  const float* g2  = (const float*)d_in[18];
  const float* be2 = (const float*)d_in[19];
  const float* m2  = (const float*)d_in[20];
  const float* v2  = (const float*)d_in[21];
  const float* g3  = (const float*)d_in[22];
  const float* be3 = (const float*)d_in[23];
  const float* m3  = (const float*)d_in[24];
  const float* v3  = (const float*)d_in[25];

  const int N = in_sizes[0] / 128;
  const int E = in_sizes[1] / 2;
  const int Etot = E + N;                   // self-loops folded in
  const int* srcp = ei;
  const int* dstp = ei + E;
  const int NB = (N + 255) >> BSH;
  const int echunk = (E + NBLK - 1) / NBLK;
  const int nchunk = (N + NBLK - 1) / NBLK;

  size_t off = 0;
  auto carve = [&](size_t bytes) {
    void* p = (char*)d_ws + off;
    off += (bytes + 255) & ~(size_t)255;
    return p;
  };
  unsigned short* Xb  = (unsigned short*)carve((size_t)N * 128 * 2);
  unsigned short* Yb  = (unsigned short*)carve((size_t)N * 128 * 2);
  float* esb  = (float*)carve((size_t)N * 2 * 4);
  float* edb  = (float*)carve((size_t)N * 2 * 4);
  int*   rowp = (int*)carve((size_t)(N + 1) * 4);
  int*   col  = (int*)carve((size_t)Etot * 4);
  unsigned* binned = (unsigned*)carve((size_t)Etot * 4);
  int* T = (int*)carve(512 * 4);
  int* B = (int*)carve(513 * 4);
  int* C = (int*)carve(512 * 4);
  unsigned short* Wt1 = (unsigned short*)carve(128 * 128 * 2);
  unsigned short* Wt2 = (unsigned short*)carve(128 * 128 * 2);
  unsigned short* Wt3 = (unsigned short*)carve(128 * 64 * 2);
  (void)ws_size; (void)n_in; (void)out_size;

  // CSR build (+ fused weight prep)
  hipMemsetAsync(T, 0, NB * 4, stream);
  bucket_hist<<<NBLK + 160, 256, 0, stream>>>(dstp, T, E, N, NB, echunk, nchunk,
                                              w1, w2, w3, Wt1, Wt2, Wt3);
  scan_small<<<1, 512, 0, stream>>>(T, B, C, NB);
  bucketB2<<<NBLK, 256, 0, stream>>>(srcp, dstp, C, binned, E, N, NB, echunk, nchunk);
  bucketC2<<<NB, 256, 0, stream>>>(binned, B, rowp, col, N);

  const int gemm_grid = (N + 127) / 128;
  const int agg_grid  = (N + 3) / 4;

  // ---- layer 1 (fp32 input, conversion fused) ----
  gemm_mfma<128, true><<<gemm_grid, 256, 0, stream>>>(x, Wt1, Yb, N, as1, ad1, esb, edb);
  aggregate2<<<agg_grid, 256, 0, stream>>>(Yb, esb, edb, rowp, col, b1, g1, be1, m1, v1,
                                           (uint4*)Xb, N);
  // ---- layer 2 ----
  gemm_mfma<128, false><<<gemm_grid, 256, 0, stream>>>(Xb, Wt2, Yb, N, as2, ad2, esb, edb);
  aggregate2<<<agg_grid, 256, 0, stream>>>(Yb, esb, edb, rowp, col, b2, g2, be2, m2, v2,
                                           (uint4*)Xb, N);
  // ---- layer 3 ----
  gemm_mfma<64, false><<<gemm_grid, 256, 0, stream>>>(Xb, Wt3, Yb, N, as3, ad3, esb, edb);
  aggregate1<<<agg_grid, 256, 0, stream>>>(Yb, esb, edb, rowp, col, b3, g3, be3, m3, v3,
                                           (float*)d_out, N);
}

// Round 9
// 324.134 us; speedup vs baseline: 1.1220x; 1.0745x over previous
//
#include <hip/hip_runtime.h>
#include <hip/hip_bf16.h>
#include <cstdint>
#include <cstddef>

#define NBLK 512          // binning blocks
#define BSH 8             // bucket shift: 256 nodes per bucket
#define CAPSH 13          // bucket capacity shift (8192 slots)
#define CAP (1 << CAPSH)

typedef short bf16x8 __attribute__((ext_vector_type(8)));
typedef float f32x4 __attribute__((ext_vector_type(4)));

__device__ __forceinline__ float leaky02(float x) { return x > 0.f ? x : 0.2f * x; }
__device__ __forceinline__ float bflo(unsigned u) { return __uint_as_float(u << 16); }
__device__ __forceinline__ float bfhi(unsigned u) { return __uint_as_float(u & 0xFFFF0000u); }
__device__ __forceinline__ unsigned short f2bf(float f) {
  __hip_bfloat16 h = __float2bfloat16(f);
  return *(unsigned short*)&h;
}
__device__ __forceinline__ unsigned pack2bf(float a, float b) {
  return (unsigned)f2bf(a) | ((unsigned)f2bf(b) << 16);
}

// ---------------- GEMM device body: Y[n,NO](bf16) = X[n,128] @ W, fused es/ed ----------------
template<int NO, bool F32IN>
__device__ void gemm_body(int bx, const void* __restrict__ Xp,
                          const unsigned short* __restrict__ Wt,
                          unsigned short* __restrict__ Y, int n,
                          const float* __restrict__ as, const float* __restrict__ ad,
                          float* __restrict__ es, float* __restrict__ ed) {
  constexpr int NT = NO / 16;
  const int wid = threadIdx.x >> 6, lane = threadIdx.x & 63;
  const int wr0 = (bx * 4 + wid) * 32;
  if (wr0 >= n) return;
  const int cl = lane & 15, kg = lane >> 4;

  int r0c = wr0 + cl;      if (r0c > n - 1) r0c = n - 1;
  int r1c = wr0 + 16 + cl; if (r1c > n - 1) r1c = n - 1;

  f32x4 acc[2][NT] = {};
  const unsigned short* Xb = (const unsigned short*)Xp;
  const float* Xf = (const float*)Xp;

#pragma unroll
  for (int ks = 0; ks < 4; ++ks) {
    bf16x8 a0, a1;
    if constexpr (F32IN) {
      const float* p0 = Xf + (size_t)r0c * 128 + kg * 8 + ks * 32;
      const float* p1 = Xf + (size_t)r1c * 128 + kg * 8 + ks * 32;
      float4 u0 = *(const float4*)p0, u1 = *(const float4*)(p0 + 4);
      float4 w0 = *(const float4*)p1, w1 = *(const float4*)(p1 + 4);
      a0[0] = (short)f2bf(u0.x); a0[1] = (short)f2bf(u0.y); a0[2] = (short)f2bf(u0.z); a0[3] = (short)f2bf(u0.w);
      a0[4] = (short)f2bf(u1.x); a0[5] = (short)f2bf(u1.y); a0[6] = (short)f2bf(u1.z); a0[7] = (short)f2bf(u1.w);
      a1[0] = (short)f2bf(w0.x); a1[1] = (short)f2bf(w0.y); a1[2] = (short)f2bf(w0.z); a1[3] = (short)f2bf(w0.w);
      a1[4] = (short)f2bf(w1.x); a1[5] = (short)f2bf(w1.y); a1[6] = (short)f2bf(w1.z); a1[7] = (short)f2bf(w1.w);
    } else {
      a0 = *(const bf16x8*)(Xb + (size_t)r0c * 128 + kg * 8 + ks * 32);
      a1 = *(const bf16x8*)(Xb + (size_t)r1c * 128 + kg * 8 + ks * 32);
    }
#pragma unroll
    for (int t = 0; t < NT; ++t) {
      bf16x8 bb = *(const bf16x8*)(Wt + (size_t)(cl + t * 16) * 128 + kg * 8 + ks * 32);
      acc[0][t] = __builtin_amdgcn_mfma_f32_16x16x32_bf16(a0, bb, acc[0][t], 0, 0, 0);
      acc[1][t] = __builtin_amdgcn_mfma_f32_16x16x32_bf16(a1, bb, acc[1][t], 0, 0, 0);
    }
  }

  float asv[NT], adv[NT];
#pragma unroll
  for (int t = 0; t < NT; ++t) { asv[t] = as[t * 16 + cl]; adv[t] = ad[t * 16 + cl]; }

#pragma unroll
  for (int s = 0; s < 2; ++s) {
#pragma unroll
    for (int rg = 0; rg < 4; ++rg) {
      int r = wr0 + s * 16 + kg * 4 + rg;
      float ps0 = 0.f, pd0 = 0.f, ps1 = 0.f, pd1 = 0.f;
#pragma unroll
      for (int t = 0; t < NT; ++t) {
        float a = acc[s][t][rg];
        if (NO == 128 && t >= 4) { ps1 = fmaf(a, asv[t], ps1); pd1 = fmaf(a, adv[t], pd1); }
        else                     { ps0 = fmaf(a, asv[t], ps0); pd0 = fmaf(a, adv[t], pd0); }
      }
#pragma unroll
      for (int o = 8; o; o >>= 1) {
        ps0 += __shfl_xor(ps0, o); pd0 += __shfl_xor(pd0, o);
        if (NO == 128) { ps1 += __shfl_xor(ps1, o); pd1 += __shfl_xor(pd1, o); }
      }
      if (r < n) {
        if (cl == 0) {
          if (NO == 128) {
            es[(size_t)r * 2] = ps0; es[(size_t)r * 2 + 1] = ps1;
            ed[(size_t)r * 2] = pd0; ed[(size_t)r * 2 + 1] = pd1;
          } else {
            es[r] = ps0; ed[r] = pd0;
          }
        }
#pragma unroll
        for (int t = 0; t < NT; ++t)
          Y[(size_t)r * NO + t * 16 + cl] = f2bf(acc[s][t][rg]);
      }
    }
  }
}

// ---------------- mega kernel 1: bucketB3 (binning) + prep_w  (pure producers, no race) ----------------
__launch_bounds__(256)
__global__ void mega1(const int* __restrict__ src, const int* __restrict__ dst,
                      int* __restrict__ T, unsigned* __restrict__ binned,
                      int E, int N, int NB, int echunk, int nchunk,
                      const float* __restrict__ w1, const float* __restrict__ w2,
                      const float* __restrict__ w3,
                      unsigned short* __restrict__ t1, unsigned short* __restrict__ t2,
                      unsigned short* __restrict__ t3) {
  int b = blockIdx.x, t = threadIdx.x;
  if (b >= NBLK) {                          // prep_w: W[128][NO] fp32 -> Wt[NO][128] bf16
    int bb = b - NBLK;
    const float* W; unsigned short* Tw; int NO; int e;
    if (bb < 64)      { W = w1; Tw = t1; NO = 128; e = bb * 256 + t; }
    else if (bb < 128){ W = w2; Tw = t2; NO = 128; e = (bb - 64) * 256 + t; }
    else              { W = w3; Tw = t3; NO = 64;  e = (bb - 128) * 256 + t; }
    int c = e >> 7, k = e & 127;
    Tw[c * 128 + k] = f2bf(W[k * NO + c]);
    return;
  }
  // bucketB3: one-pass bin with gapped bucket slots (capacity CAP each)
  __shared__ int hist[512];
  __shared__ int cur[512];
  hist[t] = 0; hist[t + 256] = 0;
  __syncthreads();
  int e0 = b * echunk, e1 = min(E, e0 + echunk);
  for (int e = e0 + t; e < e1; e += 256) atomicAdd(&hist[dst[e] >> BSH], 1);
  int n0 = b * nchunk, n1 = min(N, n0 + nchunk);
  for (int nn = n0 + t; nn < n1; nn += 256) atomicAdd(&hist[nn >> BSH], 1);
  __syncthreads();
  for (int k = t; k < 512; k += 256) {
    int c = hist[k];
    cur[k] = c ? (k << CAPSH) + atomicAdd(&T[k], c) : 0;
  }
  __syncthreads();
  for (int e = e0 + t; e < e1; e += 256) {
    int d = dst[e];
    int k = d >> BSH;
    int pos = atomicAdd(&cur[k], 1);
    binned[pos] = (unsigned)src[e] | ((unsigned)(d & 255) << 24);
  }
  for (int nn = n0 + t; nn < n1; nn += 256) {
    int k = nn >> BSH;
    int pos = atomicAdd(&cur[k], 1);
    binned[pos] = (unsigned)nn | ((unsigned)(nn & 255) << 24);
  }
}

// ---------------- mega kernel 2: bucketC3 sort  ∥  layer-1 GEMM (Wt1 from mega1, safe) ----------------
__launch_bounds__(256)
__global__ void mega2(unsigned* __restrict__ binned, const int* __restrict__ T,
                      int* __restrict__ rowp, int* __restrict__ rowe, int N, int NB,
                      const float* __restrict__ x, const unsigned short* __restrict__ Wt1,
                      unsigned short* __restrict__ Y,
                      const float* __restrict__ as1, const float* __restrict__ ad1,
                      float* __restrict__ es, float* __restrict__ ed) {
  int b = blockIdx.x, t = threadIdx.x;
  if (b >= NB) {                            // layer-1 GEMM part
    gemm_body<128, true>(b - NB, x, Wt1, Y, N, as1, ad1, es, ed);
    return;
  }
  // per-bucket counting sort (LDS-staged) -> rowp/rowe + col (in-place)
  __shared__ unsigned pay[CAP];
  __shared__ int cnt2[256];
  __shared__ int cur2[256];
  __shared__ int wsum[4];
  int k = b;
  int base = k << CAPSH;
  int cnt = T[k]; if (cnt > CAP) cnt = CAP;
  cnt2[t] = 0;
  __syncthreads();
  for (int e = t; e < cnt; e += 256) {
    unsigned p = binned[base + e];
    pay[e] = p;
    atomicAdd(&cnt2[p >> 24], 1);
  }
  __syncthreads();
  int v = cnt2[t];
  int incl = v;
  int lane = t & 63, wid = t >> 6;
  for (int off = 1; off < 64; off <<= 1) {
    int o = __shfl_up(incl, off);
    if (lane >= off) incl += o;
  }
  if (lane == 63) wsum[wid] = incl;
  __syncthreads();
  if (t == 0) { int r = 0; for (int i = 0; i < 4; ++i) { int x2 = wsum[i]; wsum[i] = r; r += x2; } }
  __syncthreads();
  int excl = incl - v + wsum[wid];
  int g = (k << BSH) + t;
  if (g < N) { rowp[g] = base + excl; rowe[g] = base + excl + v; }
  cur2[t] = excl;
  __syncthreads();
  for (int e = t; e < cnt; e += 256) {
    unsigned p = pay[e];
    int pos = atomicAdd(&cur2[p >> 24], 1);
    binned[base + pos] = p & 0xFFFFFFu;    // col aliases binned (source staged in LDS)
  }
}

// ---------------- standalone GEMM wrapper (layers 2,3) ----------------
template<int NO, bool F32IN>
__launch_bounds__(256)
__global__ void gemm_mfma(const void* __restrict__ Xp,
                          const unsigned short* __restrict__ Wt,
                          unsigned short* __restrict__ Y, int n,
                          const float* __restrict__ as, const float* __restrict__ ad,
                          float* __restrict__ es, float* __restrict__ ed) {
  gemm_body<NO, F32IN>(blockIdx.x, Xp, Wt, Y, n, as, ad, es, ed);
}

// ---------------- aggregation H=2: lane-quarters, uint4 rows (4 edges/load) ----------------
__launch_bounds__(256)
__global__ void aggregate2(const unsigned short* __restrict__ xl, const float* __restrict__ es,
                           const float* __restrict__ ed, const int* __restrict__ rowp,
                           const int* __restrict__ rowe,
                           const int* __restrict__ col, const float* __restrict__ bias,
                           const float* __restrict__ g, const float* __restrict__ be,
                           const float* __restrict__ m, const float* __restrict__ v,
                           uint4* __restrict__ out, int n) {
  int node = (blockIdx.x * blockDim.x + threadIdx.x) >> 6;
  int lane = threadIdx.x & 63;
  if (node >= n) return;
  const uint4* xr = (const uint4*)xl;       // row = 16 uint4 (128 bf16)
  int beg = rowp[node], end = rowe[node];
  float2 edv = *(const float2*)&ed[(size_t)node * 2];
  const int q = lane >> 4, hl = lane & 15;

  float acc[8] = {0.f, 0.f, 0.f, 0.f, 0.f, 0.f, 0.f, 0.f};
  float dl0 = 0.f, dl1 = 0.f;

  for (int cb = beg; cb < end; cb += 64) {
    int idx = cb + lane;
    int s = 0; float w0 = 0.f, w1 = 0.f;
    if (idx < end) {
      s = col[idx];
      float2 e2 = *(const float2*)&es[(size_t)s * 2];
      w0 = __expf(leaky02(e2.x + edv.x));
      w1 = __expf(leaky02(e2.y + edv.y));
    }
    dl0 += w0; dl1 += w1;
    int cend = end - cb; if (cend > 64) cend = 64;
    int i = 0;
    for (; i + 8 <= cend; i += 8) {
      int j0 = i + q, j1 = i + 4 + q;
      int s0 = __shfl(s, j0), s1 = __shfl(s, j1);
      uint4 v0 = xr[(size_t)s0 * 16 + hl];
      uint4 v1 = xr[(size_t)s1 * 16 + hl];
      float w00 = __shfl(w0, j0), w01 = __shfl(w1, j0);
      float w10 = __shfl(w0, j1), w11 = __shfl(w1, j1);
      float W0 = (hl < 8) ? w00 : w01;
      float W1 = (hl < 8) ? w10 : w11;
      acc[0] = fmaf(W0, bflo(v0.x), acc[0]); acc[1] = fmaf(W0, bfhi(v0.x), acc[1]);
      acc[2] = fmaf(W0, bflo(v0.y), acc[2]); acc[3] = fmaf(W0, bfhi(v0.y), acc[3]);
      acc[4] = fmaf(W0, bflo(v0.z), acc[4]); acc[5] = fmaf(W0, bfhi(v0.z), acc[5]);
      acc[6] = fmaf(W0, bflo(v0.w), acc[6]); acc[7] = fmaf(W0, bfhi(v0.w), acc[7]);
      acc[0] = fmaf(W1, bflo(v1.x), acc[0]); acc[1] = fmaf(W1, bfhi(v1.x), acc[1]);
      acc[2] = fmaf(W1, bflo(v1.y), acc[2]); acc[3] = fmaf(W1, bfhi(v1.y), acc[3]);
      acc[4] = fmaf(W1, bflo(v1.z), acc[4]); acc[5] = fmaf(W1, bfhi(v1.z), acc[5]);
      acc[6] = fmaf(W1, bflo(v1.w), acc[6]); acc[7] = fmaf(W1, bfhi(v1.w), acc[7]);
    }
    for (; i < cend; i += 4) {
      int j = i + q;
      int s0 = __shfl(s, j);
      uint4 v0 = xr[(size_t)s0 * 16 + hl];
      float w00 = __shfl(w0, j), w01 = __shfl(w1, j);
      float W0 = (hl < 8) ? w00 : w01;
      acc[0] = fmaf(W0, bflo(v0.x), acc[0]); acc[1] = fmaf(W0, bfhi(v0.x), acc[1]);
      acc[2] = fmaf(W0, bflo(v0.y), acc[2]); acc[3] = fmaf(W0, bfhi(v0.y), acc[3]);
      acc[4] = fmaf(W0, bflo(v0.z), acc[4]); acc[5] = fmaf(W0, bfhi(v0.z), acc[5]);
      acc[6] = fmaf(W0, bflo(v0.w), acc[6]); acc[7] = fmaf(W0, bfhi(v0.w), acc[7]);
    }
  }

#pragma unroll
  for (int k2 = 0; k2 < 8; ++k2) {
    acc[k2] += __shfl_xor(acc[k2], 16);
    acc[k2] += __shfl_xor(acc[k2], 32);
  }
#pragma unroll
  for (int o = 32; o; o >>= 1) { dl0 += __shfl_xor(dl0, o); dl1 += __shfl_xor(dl1, o); }

  if (q == 0) {
    int c0 = hl * 8;
    float den = (hl < 8) ? dl0 : dl1;
    float inv = 1.f / (den + 1e-16f);
    float4 bi0 = *(const float4*)&bias[c0], bi1 = *(const float4*)&bias[c0 + 4];
    float4 mm0 = *(const float4*)&m[c0],    mm1 = *(const float4*)&m[c0 + 4];
    float4 vv0 = *(const float4*)&v[c0],    vv1 = *(const float4*)&v[c0 + 4];
    float4 gg0 = *(const float4*)&g[c0],    gg1 = *(const float4*)&g[c0 + 4];
    float4 bb0 = *(const float4*)&be[c0],   bb1 = *(const float4*)&be[c0 + 4];
    float r0 = (acc[0] * inv + bi0.x - mm0.x) * rsqrtf(vv0.x + 1e-5f) * gg0.x + bb0.x;
    float r1 = (acc[1] * inv + bi0.y - mm0.y) * rsqrtf(vv0.y + 1e-5f) * gg0.y + bb0.y;
    float r2 = (acc[2] * inv + bi0.z - mm0.z) * rsqrtf(vv0.z + 1e-5f) * gg0.z + bb0.z;
    float r3 = (acc[3] * inv + bi0.w - mm0.w) * rsqrtf(vv0.w + 1e-5f) * gg0.w + bb0.w;
    float r4 = (acc[4] * inv + bi1.x - mm1.x) * rsqrtf(vv1.x + 1e-5f) * gg1.x + bb1.x;
    float r5 = (acc[5] * inv + bi1.y - mm1.y) * rsqrtf(vv1.y + 1e-5f) * gg1.y + bb1.y;
    float r6 = (acc[6] * inv + bi1.z - mm1.z) * rsqrtf(vv1.z + 1e-5f) * gg1.z + bb1.z;
    float r7 = (acc[7] * inv + bi1.w - mm1.w) * rsqrtf(vv1.w + 1e-5f) * gg1.w + bb1.w;
    uint4 o;
    o.x = pack2bf(fmaxf(r0, 0.f), fmaxf(r1, 0.f));
    o.y = pack2bf(fmaxf(r2, 0.f), fmaxf(r3, 0.f));
    o.z = pack2bf(fmaxf(r4, 0.f), fmaxf(r5, 0.f));
    o.w = pack2bf(fmaxf(r6, 0.f), fmaxf(r7, 0.f));
    out[(size_t)node * 16 + hl] = o;
  }
}

// ---------------- aggregation H=1: lane-eighths, uint4 rows (8 edges/load) ----------------
__launch_bounds__(256)
__global__ void aggregate1(const unsigned short* __restrict__ xl, const float* __restrict__ es,
                           const float* __restrict__ ed, const int* __restrict__ rowp,
                           const int* __restrict__ rowe,
                           const int* __restrict__ col, const float* __restrict__ bias,
                           const float* __restrict__ g, const float* __restrict__ be,
                           const float* __restrict__ m, const float* __restrict__ v,
                           float* __restrict__ out, int n) {
  int node = (blockIdx.x * blockDim.x + threadIdx.x) >> 6;
  int lane = threadIdx.x & 63;
  if (node >= n) return;
  const uint4* xr = (const uint4*)xl;       // row = 8 uint4 (64 bf16)
  int beg = rowp[node], end = rowe[node];
  float edv = ed[node];
  const int g8 = lane >> 3, hl = lane & 7;

  float acc[8] = {0.f, 0.f, 0.f, 0.f, 0.f, 0.f, 0.f, 0.f};
  float dl = 0.f;

  for (int cb = beg; cb < end; cb += 64) {
    int idx = cb + lane;
    int s = 0; float w = 0.f;
    if (idx < end) {
      s = col[idx];
      w = __expf(leaky02(es[s] + edv));
    }
    dl += w;
    int cend = end - cb; if (cend > 64) cend = 64;
    int i = 0;
    for (; i + 16 <= cend; i += 16) {
      int j0 = i + g8, j1 = i + 8 + g8;
      int s0 = __shfl(s, j0), s1 = __shfl(s, j1);
      uint4 v0 = xr[(size_t)s0 * 8 + hl];
      uint4 v1 = xr[(size_t)s1 * 8 + hl];
      float W0 = __shfl(w, j0), W1 = __shfl(w, j1);
      acc[0] = fmaf(W0, bflo(v0.x), acc[0]); acc[1] = fmaf(W0, bfhi(v0.x), acc[1]);
      acc[2] = fmaf(W0, bflo(v0.y), acc[2]); acc[3] = fmaf(W0, bfhi(v0.y), acc[3]);
      acc[4] = fmaf(W0, bflo(v0.z), acc[4]); acc[5] = fmaf(W0, bfhi(v0.z), acc[5]);
      acc[6] = fmaf(W0, bflo(v0.w), acc[6]); acc[7] = fmaf(W0, bfhi(v0.w), acc[7]);
      acc[0] = fmaf(W1, bflo(v1.x), acc[0]); acc[1] = fmaf(W1, bfhi(v1.x), acc[1]);
      acc[2] = fmaf(W1, bflo(v1.y), acc[2]); acc[3] = fmaf(W1, bfhi(v1.y), acc[3]);
      acc[4] = fmaf(W1, bflo(v1.z), acc[4]); acc[5] = fmaf(W1, bfhi(v1.z), acc[5]);
      acc[6] = fmaf(W1, bflo(v1.w), acc[6]); acc[7] = fmaf(W1, bfhi(v1.w), acc[7]);
    }
    for (; i < cend; i += 8) {
      int j = i + g8;
      int s0 = __shfl(s, j);
      uint4 v0 = xr[(size_t)s0 * 8 + hl];
      float W0 = __shfl(w, j);
      acc[0] = fmaf(W0, bflo(v0.x), acc[0]); acc[1] = fmaf(W0, bfhi(v0.x), acc[1]);
      acc[2] = fmaf(W0, bflo(v0.y), acc[2]); acc[3] = fmaf(W0, bfhi(v0.y), acc[3]);
      acc[4] = fmaf(W0, bflo(v0.z), acc[4]); acc[5] = fmaf(W0, bfhi(v0.z), acc[5]);
      acc[6] = fmaf(W0, bflo(v0.w), acc[6]); acc[7] = fmaf(W0, bfhi(v0.w), acc[7]);
    }
  }

#pragma unroll
  for (int k2 = 0; k2 < 8; ++k2) {
    acc[k2] += __shfl_xor(acc[k2], 8);
    acc[k2] += __shfl_xor(acc[k2], 16);
    acc[k2] += __shfl_xor(acc[k2], 32);
  }
#pragma unroll
  for (int o = 32; o; o >>= 1) dl += __shfl_xor(dl, o);

  if (lane < 8) {
    int c0 = hl * 8;
    float inv = 1.f / (dl + 1e-16f);
    float4 bi0 = *(const float4*)&bias[c0], bi1 = *(const float4*)&bias[c0 + 4];
    float4 mm0 = *(const float4*)&m[c0],    mm1 = *(const float4*)&m[c0 + 4];
    float4 vv0 = *(const float4*)&v[c0],    vv1 = *(const float4*)&v[c0 + 4];
    float4 gg0 = *(const float4*)&g[c0],    gg1 = *(const float4*)&g[c0 + 4];
    float4 bb0 = *(const float4*)&be[c0],   bb1 = *(const float4*)&be[c0 + 4];
    float4 ra, rb;
    ra.x = (acc[0] * inv + bi0.x - mm0.x) * rsqrtf(vv0.x + 1e-5f) * gg0.x + bb0.x;
    ra.y = (acc[1] * inv + bi0.y - mm0.y) * rsqrtf(vv0.y + 1e-5f) * gg0.y + bb0.y;
    ra.z = (acc[2] * inv + bi0.z - mm0.z) * rsqrtf(vv0.z + 1e-5f) * gg0.z + bb0.z;
    ra.w = (acc[3] * inv + bi0.w - mm0.w) * rsqrtf(vv0.w + 1e-5f) * gg0.w + bb0.w;
    rb.x = (acc[4] * inv + bi1.x - mm1.x) * rsqrtf(vv1.x + 1e-5f) * gg1.x + bb1.x;
    rb.y = (acc[5] * inv + bi1.y - mm1.y) * rsqrtf(vv1.y + 1e-5f) * gg1.y + bb1.y;
    rb.z = (acc[6] * inv + bi1.z - mm1.z) * rsqrtf(vv1.z + 1e-5f) * gg1.z + bb1.z;
    rb.w = (acc[7] * inv + bi1.w - mm1.w) * rsqrtf(vv1.w + 1e-5f) * gg1.w + bb1.w;
    float4* op = (float4*)(out + (size_t)node * 64 + c0);
    op[0] = ra; op[1] = rb;
  }
}

extern "C" void kernel_launch(void* const* d_in, const int* in_sizes, int n_in,
                              void* d_out, int out_size, void* d_ws, size_t ws_size,
                              hipStream_t stream) {
  const float* x   = (const float*)d_in[0];
  const int*   ei  = (const int*)d_in[1];
  const float* w1  = (const float*)d_in[2];
  const float* as1 = (const float*)d_in[3];
  const float* ad1 = (const float*)d_in[4];
  const float* b1  = (const float*)d_in[5];
  const float* w2  = (const float*)d_in[6];
  const float* as2 = (const float*)d_in[7];
  const float* ad2 = (const float*)d_in[8];
  const float* b2  = (const float*)d_in[9];
  const float* w3  = (const float*)d_in[10];
  const float* as3 = (const float*)d_in[11];
  const float* ad3 = (const float*)d_in[12];
  const float* b3  = (const float*)d_in[13];
  const float* g1  = (const float*)d_in[14];
  const float* be1 = (const float*)d_in[15];
  const float* m1  = (const float*)d_in[16];
  const float* v1  = (const float*)d_in[17];
  const float* g2  = (const float*)d_in[18];
  const float* be2 = (const float*)d_in[19];
  const float* m2  = (const float*)d_in[20];
  const float* v2  = (const float*)d_in[21];
  const float* g3  = (const float*)d_in[22];
  const float* be3 = (const float*)d_in[23];
  const float* m3  = (const float*)d_in[24];
  const float* v3  = (const float*)d_in[25];

  const int N = in_sizes[0] / 128;
  const int E = in_sizes[1] / 2;
  const int* srcp = ei;
  const int* dstp = ei + E;
  const int NB = (N + 255) >> BSH;          // buckets of 256 nodes
  const int echunk = (E + NBLK - 1) / NBLK;
  const int nchunk = (N + NBLK - 1) / NBLK;

  size_t off = 0;
  auto carve = [&](size_t bytes) {
    void* p = (char*)d_ws + off;
    off += (bytes + 255) & ~(size_t)255;
    return p;
  };
  unsigned short* Xb  = (unsigned short*)carve((size_t)N * 128 * 2);
  unsigned short* Yb  = (unsigned short*)carve((size_t)N * 128 * 2);
  float* esb  = (float*)carve((size_t)N * 2 * 4);
  float* edb  = (float*)carve((size_t)N * 2 * 4);
  int*   rowp = (int*)carve((size_t)N * 4);
  int*   rowe = (int*)carve((size_t)N * 4);
  unsigned* binned = (unsigned*)carve((size_t)NB * CAP * 4);   // also serves as col (in-place)
  int* T = (int*)carve(512 * 4);
  unsigned short* Wt1 = (unsigned short*)carve(128 * 128 * 2);
  unsigned short* Wt2 = (unsigned short*)carve(128 * 128 * 2);
  unsigned short* Wt3 = (unsigned short*)carve(128 * 64 * 2);
  (void)ws_size; (void)n_in; (void)out_size;
  int* col = (int*)binned;

  const int gemm_grid = (N + 127) / 128;
  const int agg_grid  = (N + 3) / 4;

  // CSR binning + weight prep (producers only)
  hipMemsetAsync(T, 0, NB * 4, stream);
  mega1<<<NBLK + 160, 256, 0, stream>>>(srcp, dstp, T, binned, E, N, NB, echunk, nchunk,
                                        w1, w2, w3, Wt1, Wt2, Wt3);
  // bucket sort ∥ layer-1 GEMM (both consume mega1 outputs across dispatch boundary)
  mega2<<<NB + gemm_grid, 256, 0, stream>>>(binned, T, rowp, rowe, N, NB,
                                            x, Wt1, Yb, as1, ad1, esb, edb);

  // ---- layer 1 aggregate ----
  aggregate2<<<agg_grid, 256, 0, stream>>>(Yb, esb, edb, rowp, rowe, col, b1, g1, be1, m1, v1,
                                           (uint4*)Xb, N);
  // ---- layer 2 ----
  gemm_mfma<128, false><<<gemm_grid, 256, 0, stream>>>(Xb, Wt2, Yb, N, as2, ad2, esb, edb);
  aggregate2<<<agg_grid, 256, 0, stream>>>(Yb, esb, edb, rowp, rowe, col, b2, g2, be2, m2, v2,
                                           (uint4*)Xb, N);
  // ---- layer 3 ----
  gemm_mfma<64, false><<<gemm_grid, 256, 0, stream>>>(Xb, Wt3, Yb, N, as3, ad3, esb, edb);
  aggregate1<<<agg_grid, 256, 0, stream>>>(Yb, esb, edb, rowp, rowe, col, b3, g3, be3, m3, v3,
                                           (float*)d_out, N);
}

// Round 10
// 306.482 us; speedup vs baseline: 1.1866x; 1.0576x over previous
//
#include <hip/hip_runtime.h>
#include <hip/hip_bf16.h>
#include <cstdint>
#include <cstddef>

#define NBLK 512          // binning blocks
#define BSH 8             // bucket shift: 256 nodes per bucket
#define CAPSH 13          // bucket capacity shift (8192 slots)
#define CAP (1 << CAPSH)
#define WLD 136           // LDS weight row stride (shorts): 272B, ~conflict-free

typedef short bf16x8 __attribute__((ext_vector_type(8)));
typedef float f32x4 __attribute__((ext_vector_type(4)));

__device__ __forceinline__ float leaky02(float x) { return x > 0.f ? x : 0.2f * x; }
__device__ __forceinline__ float bflo(unsigned u) { return __uint_as_float(u << 16); }
__device__ __forceinline__ float bfhi(unsigned u) { return __uint_as_float(u & 0xFFFF0000u); }
__device__ __forceinline__ unsigned short f2bf(float f) {
  __hip_bfloat16 h = __float2bfloat16(f);
  return *(unsigned short*)&h;
}
__device__ __forceinline__ unsigned pack2bf(float a, float b) {
  return (unsigned)f2bf(a) | ((unsigned)f2bf(b) << 16);
}

// ---------------- stage Wt[NO][128] (bf16) into LDS with padded stride ----------------
template<int NO>
__device__ __forceinline__ void stage_w(unsigned short* sW, const unsigned short* Wt) {
  for (int i = threadIdx.x; i < NO * 16; i += 256) {
    int row = i >> 4, c8 = (i & 15) * 8;
    *(uint4*)&sW[row * WLD + c8] = *(const uint4*)&Wt[(size_t)row * 128 + c8];
  }
}

// ---------------- GEMM device body: Y[n,NO](bf16) = X[n,128] @ W(LDS), fused es/ed ----------------
template<int NO, bool F32IN>
__device__ void gemm_body(int bx, const void* __restrict__ Xp,
                          const unsigned short* sWt,           // LDS, stride WLD
                          unsigned short* __restrict__ Y, int n,
                          const float* __restrict__ as, const float* __restrict__ ad,
                          float* __restrict__ es, float* __restrict__ ed) {
  constexpr int NT = NO / 16;
  const int wid = threadIdx.x >> 6, lane = threadIdx.x & 63;
  const int wr0 = (bx * 4 + wid) * 32;
  if (wr0 >= n) return;
  const int cl = lane & 15, kg = lane >> 4;

  int r0c = wr0 + cl;      if (r0c > n - 1) r0c = n - 1;
  int r1c = wr0 + 16 + cl; if (r1c > n - 1) r1c = n - 1;

  f32x4 acc[2][NT] = {};
  const unsigned short* Xb = (const unsigned short*)Xp;
  const float* Xf = (const float*)Xp;

#pragma unroll
  for (int ks = 0; ks < 4; ++ks) {
    bf16x8 a0, a1;
    if constexpr (F32IN) {
      const float* p0 = Xf + (size_t)r0c * 128 + kg * 8 + ks * 32;
      const float* p1 = Xf + (size_t)r1c * 128 + kg * 8 + ks * 32;
      float4 u0 = *(const float4*)p0, u1 = *(const float4*)(p0 + 4);
      float4 w0 = *(const float4*)p1, w1 = *(const float4*)(p1 + 4);
      a0[0] = (short)f2bf(u0.x); a0[1] = (short)f2bf(u0.y); a0[2] = (short)f2bf(u0.z); a0[3] = (short)f2bf(u0.w);
      a0[4] = (short)f2bf(u1.x); a0[5] = (short)f2bf(u1.y); a0[6] = (short)f2bf(u1.z); a0[7] = (short)f2bf(u1.w);
      a1[0] = (short)f2bf(w0.x); a1[1] = (short)f2bf(w0.y); a1[2] = (short)f2bf(w0.z); a1[3] = (short)f2bf(w0.w);
      a1[4] = (short)f2bf(w1.x); a1[5] = (short)f2bf(w1.y); a1[6] = (short)f2bf(w1.z); a1[7] = (short)f2bf(w1.w);
    } else {
      a0 = *(const bf16x8*)(Xb + (size_t)r0c * 128 + kg * 8 + ks * 32);
      a1 = *(const bf16x8*)(Xb + (size_t)r1c * 128 + kg * 8 + ks * 32);
    }
#pragma unroll
    for (int t = 0; t < NT; ++t) {
      bf16x8 bb = *(const bf16x8*)(sWt + (cl + t * 16) * WLD + kg * 8 + ks * 32);
      acc[0][t] = __builtin_amdgcn_mfma_f32_16x16x32_bf16(a0, bb, acc[0][t], 0, 0, 0);
      acc[1][t] = __builtin_amdgcn_mfma_f32_16x16x32_bf16(a1, bb, acc[1][t], 0, 0, 0);
    }
  }

  float asv[NT], adv[NT];
#pragma unroll
  for (int t = 0; t < NT; ++t) { asv[t] = as[t * 16 + cl]; adv[t] = ad[t * 16 + cl]; }

#pragma unroll
  for (int s = 0; s < 2; ++s) {
#pragma unroll
    for (int rg = 0; rg < 4; ++rg) {
      int r = wr0 + s * 16 + kg * 4 + rg;
      float ps0 = 0.f, pd0 = 0.f, ps1 = 0.f, pd1 = 0.f;
#pragma unroll
      for (int t = 0; t < NT; ++t) {
        float a = acc[s][t][rg];
        if (NO == 128 && t >= 4) { ps1 = fmaf(a, asv[t], ps1); pd1 = fmaf(a, adv[t], pd1); }
        else                     { ps0 = fmaf(a, asv[t], ps0); pd0 = fmaf(a, adv[t], pd0); }
      }
#pragma unroll
      for (int o = 8; o; o >>= 1) {
        ps0 += __shfl_xor(ps0, o); pd0 += __shfl_xor(pd0, o);
        if (NO == 128) { ps1 += __shfl_xor(ps1, o); pd1 += __shfl_xor(pd1, o); }
      }
      if (r < n) {
        if (cl == 0) {
          if (NO == 128) {
            es[(size_t)r * 2] = ps0; es[(size_t)r * 2 + 1] = ps1;
            ed[(size_t)r * 2] = pd0; ed[(size_t)r * 2 + 1] = pd1;
          } else {
            es[r] = ps0; ed[r] = pd0;
          }
        }
#pragma unroll
        for (int t = 0; t < NT; ++t)
          Y[(size_t)r * NO + t * 16 + cl] = f2bf(acc[s][t][rg]);
      }
    }
  }
}

// ---------------- mega kernel 1: bucketB3 (binning) + prep_w  (pure producers, no race) ----------------
__launch_bounds__(256)
__global__ void mega1(const int* __restrict__ src, const int* __restrict__ dst,
                      int* __restrict__ T, unsigned* __restrict__ binned,
                      int E, int N, int NB, int echunk, int nchunk,
                      const float* __restrict__ w1, const float* __restrict__ w2,
                      const float* __restrict__ w3,
                      unsigned short* __restrict__ t1, unsigned short* __restrict__ t2,
                      unsigned short* __restrict__ t3) {
  int b = blockIdx.x, t = threadIdx.x;
  if (b >= NBLK) {                          // prep_w: W[128][NO] fp32 -> Wt[NO][128] bf16
    int bb = b - NBLK;
    const float* W; unsigned short* Tw; int NO; int e;
    if (bb < 64)      { W = w1; Tw = t1; NO = 128; e = bb * 256 + t; }
    else if (bb < 128){ W = w2; Tw = t2; NO = 128; e = (bb - 64) * 256 + t; }
    else              { W = w3; Tw = t3; NO = 64;  e = (bb - 128) * 256 + t; }
    int c = e >> 7, k = e & 127;
    Tw[c * 128 + k] = f2bf(W[k * NO + c]);
    return;
  }
  // bucketB3: one-pass bin with gapped bucket slots (capacity CAP each)
  __shared__ int hist[512];
  __shared__ int cur[512];
  hist[t] = 0; hist[t + 256] = 0;
  __syncthreads();
  int e0 = b * echunk, e1 = min(E, e0 + echunk);
  for (int e = e0 + t; e < e1; e += 256) atomicAdd(&hist[dst[e] >> BSH], 1);
  int n0 = b * nchunk, n1 = min(N, n0 + nchunk);
  for (int nn = n0 + t; nn < n1; nn += 256) atomicAdd(&hist[nn >> BSH], 1);
  __syncthreads();
  for (int k = t; k < 512; k += 256) {
    int c = hist[k];
    cur[k] = c ? (k << CAPSH) + atomicAdd(&T[k], c) : 0;
  }
  __syncthreads();
  for (int e = e0 + t; e < e1; e += 256) {
    int d = dst[e];
    int k = d >> BSH;
    int pos = atomicAdd(&cur[k], 1);
    binned[pos] = (unsigned)src[e] | ((unsigned)(d & 255) << 24);
  }
  for (int nn = n0 + t; nn < n1; nn += 256) {
    int k = nn >> BSH;
    int pos = atomicAdd(&cur[k], 1);
    binned[pos] = (unsigned)nn | ((unsigned)(nn & 255) << 24);
  }
}

// ---------------- mega kernel 2: bucketC3 sort  ∥  layer-1 GEMM (Wt1 from mega1, safe) ----------------
__launch_bounds__(256)
__global__ void mega2(unsigned* __restrict__ binned, const int* __restrict__ T,
                      int* __restrict__ rowp, int* __restrict__ rowe, int N, int NB,
                      const float* __restrict__ x, const unsigned short* __restrict__ Wt1,
                      unsigned short* __restrict__ Y,
                      const float* __restrict__ as1, const float* __restrict__ ad1,
                      float* __restrict__ es, float* __restrict__ ed) {
  __shared__ char smem[128 * WLD * 2];      // 34.8 KB: sort payload (32 KB) or LDS weights
  int b = blockIdx.x, t = threadIdx.x;
  if (b >= NB) {                            // layer-1 GEMM part
    unsigned short* sW = (unsigned short*)smem;
    stage_w<128>(sW, Wt1);
    __syncthreads();
    gemm_body<128, true>(b - NB, x, sW, Y, N, as1, ad1, es, ed);
    return;
  }
  // per-bucket counting sort (LDS-staged) -> rowp/rowe + col (in-place)
  unsigned* pay = (unsigned*)smem;
  __shared__ int cnt2[256];
  __shared__ int cur2[256];
  __shared__ int wsum[4];
  int k = b;
  int base = k << CAPSH;
  int cnt = T[k]; if (cnt > CAP) cnt = CAP;
  cnt2[t] = 0;
  __syncthreads();
  for (int e = t; e < cnt; e += 256) {
    unsigned p = binned[base + e];
    pay[e] = p;
    atomicAdd(&cnt2[p >> 24], 1);
  }
  __syncthreads();
  int v = cnt2[t];
  int incl = v;
  int lane = t & 63, wid = t >> 6;
  for (int off = 1; off < 64; off <<= 1) {
    int o = __shfl_up(incl, off);
    if (lane >= off) incl += o;
  }
  if (lane == 63) wsum[wid] = incl;
  __syncthreads();
  if (t == 0) { int r = 0; for (int i = 0; i < 4; ++i) { int x2 = wsum[i]; wsum[i] = r; r += x2; } }
  __syncthreads();
  int excl = incl - v + wsum[wid];
  int g = (k << BSH) + t;
  if (g < N) { rowp[g] = base + excl; rowe[g] = base + excl + v; }
  cur2[t] = excl;
  __syncthreads();
  for (int e = t; e < cnt; e += 256) {
    unsigned p = pay[e];
    int pos = atomicAdd(&cur2[p >> 24], 1);
    binned[base + pos] = p & 0xFFFFFFu;    // col aliases binned (source staged in LDS)
  }
}

// ---------------- standalone GEMM wrapper (layers 2,3) with LDS weights ----------------
template<int NO, bool F32IN>
__launch_bounds__(256)
__global__ void gemm_mfma(const void* __restrict__ Xp,
                          const unsigned short* __restrict__ Wt,
                          unsigned short* __restrict__ Y, int n,
                          const float* __restrict__ as, const float* __restrict__ ad,
                          float* __restrict__ es, float* __restrict__ ed) {
  __shared__ unsigned short sW[NO * WLD];
  stage_w<NO>(sW, Wt);
  __syncthreads();
  gemm_body<NO, F32IN>(blockIdx.x, Xp, sW, Y, n, as, ad, es, ed);
}

// ---------------- aggregation H=2: lane-quarters, uint4 rows (4 edges/load) ----------------
__launch_bounds__(256)
__global__ void aggregate2(const unsigned short* __restrict__ xl, const float* __restrict__ es,
                           const float* __restrict__ ed, const int* __restrict__ rowp,
                           const int* __restrict__ rowe,
                           const int* __restrict__ col, const float* __restrict__ bias,
                           const float* __restrict__ g, const float* __restrict__ be,
                           const float* __restrict__ m, const float* __restrict__ v,
                           uint4* __restrict__ out, int n) {
  int node = (blockIdx.x * blockDim.x + threadIdx.x) >> 6;
  int lane = threadIdx.x & 63;
  if (node >= n) return;
  const uint4* xr = (const uint4*)xl;       // row = 16 uint4 (128 bf16)
  int beg = rowp[node], end = rowe[node];
  float2 edv = *(const float2*)&ed[(size_t)node * 2];
  const int q = lane >> 4, hl = lane & 15;

  float acc[8] = {0.f, 0.f, 0.f, 0.f, 0.f, 0.f, 0.f, 0.f};
  float dl0 = 0.f, dl1 = 0.f;

  for (int cb = beg; cb < end; cb += 64) {
    int idx = cb + lane;
    int s = 0; float w0 = 0.f, w1 = 0.f;
    if (idx < end) {
      s = col[idx];
      float2 e2 = *(const float2*)&es[(size_t)s * 2];
      w0 = __expf(leaky02(e2.x + edv.x));
      w1 = __expf(leaky02(e2.y + edv.y));
    }
    dl0 += w0; dl1 += w1;
    int cend = end - cb; if (cend > 64) cend = 64;
    int i = 0;
    for (; i + 8 <= cend; i += 8) {
      int j0 = i + q, j1 = i + 4 + q;
      int s0 = __shfl(s, j0), s1 = __shfl(s, j1);
      uint4 v0 = xr[(size_t)s0 * 16 + hl];
      uint4 v1 = xr[(size_t)s1 * 16 + hl];
      float w00 = __shfl(w0, j0), w01 = __shfl(w1, j0);
      float w10 = __shfl(w0, j1), w11 = __shfl(w1, j1);
      float W0 = (hl < 8) ? w00 : w01;
      float W1 = (hl < 8) ? w10 : w11;
      acc[0] = fmaf(W0, bflo(v0.x), acc[0]); acc[1] = fmaf(W0, bfhi(v0.x), acc[1]);
      acc[2] = fmaf(W0, bflo(v0.y), acc[2]); acc[3] = fmaf(W0, bfhi(v0.y), acc[3]);
      acc[4] = fmaf(W0, bflo(v0.z), acc[4]); acc[5] = fmaf(W0, bfhi(v0.z), acc[5]);
      acc[6] = fmaf(W0, bflo(v0.w), acc[6]); acc[7] = fmaf(W0, bfhi(v0.w), acc[7]);
      acc[0] = fmaf(W1, bflo(v1.x), acc[0]); acc[1] = fmaf(W1, bfhi(v1.x), acc[1]);
      acc[2] = fmaf(W1, bflo(v1.y), acc[2]); acc[3] = fmaf(W1, bfhi(v1.y), acc[3]);
      acc[4] = fmaf(W1, bflo(v1.z), acc[4]); acc[5] = fmaf(W1, bfhi(v1.z), acc[5]);
      acc[6] = fmaf(W1, bflo(v1.w), acc[6]); acc[7] = fmaf(W1, bfhi(v1.w), acc[7]);
    }
    for (; i < cend; i += 4) {
      int j = i + q;
      int s0 = __shfl(s, j);
      uint4 v0 = xr[(size_t)s0 * 16 + hl];
      float w00 = __shfl(w0, j), w01 = __shfl(w1, j);
      float W0 = (hl < 8) ? w00 : w01;
      acc[0] = fmaf(W0, bflo(v0.x), acc[0]); acc[1] = fmaf(W0, bfhi(v0.x), acc[1]);
      acc[2] = fmaf(W0, bflo(v0.y), acc[2]); acc[3] = fmaf(W0, bfhi(v0.y), acc[3]);
      acc[4] = fmaf(W0, bflo(v0.z), acc[4]); acc[5] = fmaf(W0, bfhi(v0.z), acc[5]);
      acc[6] = fmaf(W0, bflo(v0.w), acc[6]); acc[7] = fmaf(W0, bfhi(v0.w), acc[7]);
    }
  }

#pragma unroll
  for (int k2 = 0; k2 < 8; ++k2) {
    acc[k2] += __shfl_xor(acc[k2], 16);
    acc[k2] += __shfl_xor(acc[k2], 32);
  }
#pragma unroll
  for (int o = 32; o; o >>= 1) { dl0 += __shfl_xor(dl0, o); dl1 += __shfl_xor(dl1, o); }

  if (q == 0) {
    int c0 = hl * 8;
    float den = (hl < 8) ? dl0 : dl1;
    float inv = 1.f / (den + 1e-16f);
    float4 bi0 = *(const float4*)&bias[c0], bi1 = *(const float4*)&bias[c0 + 4];
    float4 mm0 = *(const float4*)&m[c0],    mm1 = *(const float4*)&m[c0 + 4];
    float4 vv0 = *(const float4*)&v[c0],    vv1 = *(const float4*)&v[c0 + 4];
    float4 gg0 = *(const float4*)&g[c0],    gg1 = *(const float4*)&g[c0 + 4];
    float4 bb0 = *(const float4*)&be[c0],   bb1 = *(const float4*)&be[c0 + 4];
    float r0 = (acc[0] * inv + bi0.x - mm0.x) * rsqrtf(vv0.x + 1e-5f) * gg0.x + bb0.x;
    float r1 = (acc[1] * inv + bi0.y - mm0.y) * rsqrtf(vv0.y + 1e-5f) * gg0.y + bb0.y;
    float r2 = (acc[2] * inv + bi0.z - mm0.z) * rsqrtf(vv0.z + 1e-5f) * gg0.z + bb0.z;
    float r3 = (acc[3] * inv + bi0.w - mm0.w) * rsqrtf(vv0.w + 1e-5f) * gg0.w + bb0.w;
    float r4 = (acc[4] * inv + bi1.x - mm1.x) * rsqrtf(vv1.x + 1e-5f) * gg1.x + bb1.x;
    float r5 = (acc[5] * inv + bi1.y - mm1.y) * rsqrtf(vv1.y + 1e-5f) * gg1.y + bb1.y;
    float r6 = (acc[6] * inv + bi1.z - mm1.z) * rsqrtf(vv1.z + 1e-5f) * gg1.z + bb1.z;
    float r7 = (acc[7] * inv + bi1.w - mm1.w) * rsqrtf(vv1.w + 1e-5f) * gg1.w + bb1.w;
    uint4 o;
    o.x = pack2bf(fmaxf(r0, 0.f), fmaxf(r1, 0.f));
    o.y = pack2bf(fmaxf(r2, 0.f), fmaxf(r3, 0.f));
    o.z = pack2bf(fmaxf(r4, 0.f), fmaxf(r5, 0.f));
    o.w = pack2bf(fmaxf(r6, 0.f), fmaxf(r7, 0.f));
    out[(size_t)node * 16 + hl] = o;
  }
}

// ---------------- aggregation H=1: lane-eighths, uint4 rows (8 edges/load) ----------------
__launch_bounds__(256)
__global__ void aggregate1(const unsigned short* __restrict__ xl, const float* __restrict__ es,
                           const float* __restrict__ ed, const int* __restrict__ rowp,
                           const int* __restrict__ rowe,
                           const int* __restrict__ col, const float* __restrict__ bias,
                           const float* __restrict__ g, const float* __restrict__ be,
                           const float* __restrict__ m, const float* __restrict__ v,
                           float* __restrict__ out, int n) {
  int node = (blockIdx.x * blockDim.x + threadIdx.x) >> 6;
  int lane = threadIdx.x & 63;
  if (node >= n) return;
  const uint4* xr = (const uint4*)xl;       // row = 8 uint4 (64 bf16)
  int beg = rowp[node], end = rowe[node];
  float edv = ed[node];
  const int g8 = lane >> 3, hl = lane & 7;

  float acc[8] = {0.f, 0.f, 0.f, 0.f, 0.f, 0.f, 0.f, 0.f};
  float dl = 0.f;

  for (int cb = beg; cb < end; cb += 64) {
    int idx = cb + lane;
    int s = 0; float w = 0.f;
    if (idx < end) {
      s = col[idx];
      w = __expf(leaky02(es[s] + edv));
    }
    dl += w;
    int cend = end - cb; if (cend > 64) cend = 64;
    int i = 0;
    for (; i + 16 <= cend; i += 16) {
      int j0 = i + g8, j1 = i + 8 + g8;
      int s0 = __shfl(s, j0), s1 = __shfl(s, j1);
      uint4 v0 = xr[(size_t)s0 * 8 + hl];
      uint4 v1 = xr[(size_t)s1 * 8 + hl];
      float W0 = __shfl(w, j0), W1 = __shfl(w, j1);
      acc[0] = fmaf(W0, bflo(v0.x), acc[0]); acc[1] = fmaf(W0, bfhi(v0.x), acc[1]);
      acc[2] = fmaf(W0, bflo(v0.y), acc[2]); acc[3] = fmaf(W0, bfhi(v0.y), acc[3]);
      acc[4] = fmaf(W0, bflo(v0.z), acc[4]); acc[5] = fmaf(W0, bfhi(v0.z), acc[5]);
      acc[6] = fmaf(W0, bflo(v0.w), acc[6]); acc[7] = fmaf(W0, bfhi(v0.w), acc[7]);
      acc[0] = fmaf(W1, bflo(v1.x), acc[0]); acc[1] = fmaf(W1, bfhi(v1.x), acc[1]);
      acc[2] = fmaf(W1, bflo(v1.y), acc[2]); acc[3] = fmaf(W1, bfhi(v1.y), acc[3]);
      acc[4] = fmaf(W1, bflo(v1.z), acc[4]); acc[5] = fmaf(W1, bfhi(v1.z), acc[5]);
      acc[6] = fmaf(W1, bflo(v1.w), acc[6]); acc[7] = fmaf(W1, bfhi(v1.w), acc[7]);
    }
    for (; i < cend; i += 8) {
      int j = i + g8;
      int s0 = __shfl(s, j);
      uint4 v0 = xr[(size_t)s0 * 8 + hl];
      float W0 = __shfl(w, j);
      acc[0] = fmaf(W0, bflo(v0.x), acc[0]); acc[1] = fmaf(W0, bfhi(v0.x), acc[1]);
      acc[2] = fmaf(W0, bflo(v0.y), acc[2]); acc[3] = fmaf(W0, bfhi(v0.y), acc[3]);
      acc[4] = fmaf(W0, bflo(v0.z), acc[4]); acc[5] = fmaf(W0, bfhi(v0.z), acc[5]);
      acc[6] = fmaf(W0, bflo(v0.w), acc[6]); acc[7] = fmaf(W0, bfhi(v0.w), acc[7]);
    }
  }

#pragma unroll
  for (int k2 = 0; k2 < 8; ++k2) {
    acc[k2] += __shfl_xor(acc[k2], 8);
    acc[k2] += __shfl_xor(acc[k2], 16);
    acc[k2] += __shfl_xor(acc[k2], 32);
  }
#pragma unroll
  for (int o = 32; o; o >>= 1) dl += __shfl_xor(dl, o);

  if (lane < 8) {
    int c0 = hl * 8;
    float inv = 1.f / (dl + 1e-16f);
    float4 bi0 = *(const float4*)&bias[c0], bi1 = *(const float4*)&bias[c0 + 4];
    float4 mm0 = *(const float4*)&m[c0],    mm1 = *(const float4*)&m[c0 + 4];
    float4 vv0 = *(const float4*)&v[c0],    vv1 = *(const float4*)&v[c0 + 4];
    float4 gg0 = *(const float4*)&g[c0],    gg1 = *(const float4*)&g[c0 + 4];
    float4 bb0 = *(const float4*)&be[c0],   bb1 = *(const float4*)&be[c0 + 4];
    float4 ra, rb;
    ra.x = (acc[0] * inv + bi0.x - mm0.x) * rsqrtf(vv0.x + 1e-5f) * gg0.x + bb0.x;
    ra.y = (acc[1] * inv + bi0.y - mm0.y) * rsqrtf(vv0.y + 1e-5f) * gg0.y + bb0.y;
    ra.z = (acc[2] * inv + bi0.z - mm0.z) * rsqrtf(vv0.z + 1e-5f) * gg0.z + bb0.z;
    ra.w = (acc[3] * inv + bi0.w - mm0.w) * rsqrtf(vv0.w + 1e-5f) * gg0.w + bb0.w;
    rb.x = (acc[4] * inv + bi1.x - mm1.x) * rsqrtf(vv1.x + 1e-5f) * gg1.x + bb1.x;
    rb.y = (acc[5] * inv + bi1.y - mm1.y) * rsqrtf(vv1.y + 1e-5f) * gg1.y + bb1.y;
    rb.z = (acc[6] * inv + bi1.z - mm1.z) * rsqrtf(vv1.z + 1e-5f) * gg1.z + bb1.z;
    rb.w = (acc[7] * inv + bi1.w - mm1.w) * rsqrtf(vv1.w + 1e-5f) * gg1.w + bb1.w;
    float4* op = (float4*)(out + (size_t)node * 64 + c0);
    op[0] = ra; op[1] = rb;
  }
}

extern "C" void kernel_launch(void* const* d_in, const int* in_sizes, int n_in,
                              void* d_out, int out_size, void* d_ws, size_t ws_size,
                              hipStream_t stream) {
  const float* x   = (const float*)d_in[0];
  const int*   ei  = (const int*)d_in[1];
  const float* w1  = (const float*)d_in[2];
  const float* as1 = (const float*)d_in[3];
  const float* ad1 = (const float*)d_in[4];
  const float* b1  = (const float*)d_in[5];
  const float* w2  = (const float*)d_in[6];
  const float* as2 = (const float*)d_in[7];
  const float* ad2 = (const float*)d_in[8];
  const float* b2  = (const float*)d_in[9];
  const float* w3  = (const float*)d_in[10];
  const float* as3 = (const float*)d_in[11];
  const float* ad3 = (const float*)d_in[12];
  const float* b3  = (const float*)d_in[13];
  const float* g1  = (const float*)d_in[14];
  const float* be1 = (const float*)d_in[15];
  const float* m1  = (const float*)d_in[16];
  const float* v1  = (const float*)d_in[17];
  const float* g2  = (const float*)d_in[18];
  const float* be2 = (const float*)d_in[19];
  const float* m2  = (const float*)d_in[20];
  const float* v2  = (const float*)d_in[21];
  const float* g3  = (const float*)d_in[22];
  const float* be3 = (const float*)d_in[23];
  const float* m3  = (const float*)d_in[24];
  const float* v3  = (const float*)d_in[25];

  const int N = in_sizes[0] / 128;
  const int E = in_sizes[1] / 2;
  const int* srcp = ei;
  const int* dstp = ei + E;
  const int NB = (N + 255) >> BSH;          // buckets of 256 nodes
  const int echunk = (E + NBLK - 1) / NBLK;
  const int nchunk = (N + NBLK - 1) / NBLK;

  size_t off = 0;
  auto carve = [&](size_t bytes) {
    void* p = (char*)d_ws + off;
    off += (bytes + 255) & ~(size_t)255;
    return p;
  };
  unsigned short* Xb  = (unsigned short*)carve((size_t)N * 128 * 2);
  unsigned short* Yb  = (unsigned short*)carve((size_t)N * 128 * 2);
  float* esb  = (float*)carve((size_t)N * 2 * 4);
  float* edb  = (float*)carve((size_t)N * 2 * 4);
  int*   rowp = (int*)carve((size_t)N * 4);
  int*   rowe = (int*)carve((size_t)N * 4);
  unsigned* binned = (unsigned*)carve((size_t)NB * CAP * 4);   // also serves as col (in-place)
  int* T = (int*)carve(512 * 4);
  unsigned short* Wt1 = (unsigned short*)carve(128 * 128 * 2);
  unsigned short* Wt2 = (unsigned short*)carve(128 * 128 * 2);
  unsigned short* Wt3 = (unsigned short*)carve(128 * 64 * 2);
  (void)ws_size; (void)n_in; (void)out_size;
  int* col = (int*)binned;

  const int gemm_grid = (N + 127) / 128;
  const int agg_grid  = (N + 3) / 4;

  // CSR binning + weight prep (producers only)
  hipMemsetAsync(T, 0, NB * 4, stream);
  mega1<<<NBLK + 160, 256, 0, stream>>>(srcp, dstp, T, binned, E, N, NB, echunk, nchunk,
                                        w1, w2, w3, Wt1, Wt2, Wt3);
  // bucket sort ∥ layer-1 GEMM (both consume mega1 outputs across dispatch boundary)
  mega2<<<NB + gemm_grid, 256, 0, stream>>>(binned, T, rowp, rowe, N, NB,
                                            x, Wt1, Yb, as1, ad1, esb, edb);

  // ---- layer 1 aggregate ----
  aggregate2<<<agg_grid, 256, 0, stream>>>(Yb, esb, edb, rowp, rowe, col, b1, g1, be1, m1, v1,
                                           (uint4*)Xb, N);
  // ---- layer 2 ----
  gemm_mfma<128, false><<<gemm_grid, 256, 0, stream>>>(Xb, Wt2, Yb, N, as2, ad2, esb, edb);
  aggregate2<<<agg_grid, 256, 0, stream>>>(Yb, esb, edb, rowp, rowe, col, b2, g2, be2, m2, v2,
                                           (uint4*)Xb, N);
  // ---- layer 3 ----
  gemm_mfma<64, false><<<gemm_grid, 256, 0, stream>>>(Xb, Wt3, Yb, N, as3, ad3, esb, edb);
  aggregate1<<<agg_grid, 256, 0, stream>>>(Yb, esb, edb, rowp, rowe, col, b3, g3, be3, m3, v3,
                                           (float*)d_out, N);
}